// Round 12
// baseline (508.273 us; speedup 1.0000x reference)
//
#include <hip/hip_runtime.h>
#include <stdint.h>

// Problem constants (fixed-size problem)
#define DM   512
#define DFF  2048
#define NH   8
#define EH   64
#define SEQ  2048
#define NBAT 2
#define NTOK (NBAT*SEQ)   // 4096
#define LOG2E 1.44269504088896340736f

typedef __attribute__((ext_vector_type(8))) short  s16x8;
typedef __attribute__((ext_vector_type(8))) __bf16 bf16x8;
typedef __attribute__((ext_vector_type(4))) float  f32x4;

__device__ __forceinline__ short f2bf(float f) {
  union { float f; unsigned int i; } c; c.f = f;
  unsigned int x = c.i;
  x += 0x7fffu + ((x >> 16) & 1u);   // RNE
  return (short)(x >> 16);
}
__device__ __forceinline__ float bf2f(short u) {
  union { unsigned int i; float f; } c;
  c.i = ((unsigned int)(unsigned short)u) << 16;
  return c.f;
}
__device__ __forceinline__ f32x4 mfma16(bf16x8 a, bf16x8 b, f32x4 c) {
  return __builtin_amdgcn_mfma_f32_16x16x32_bf16(a, b, c, 0, 0, 0);
}
// Async global->LDS, 16B per lane. LDS dest = wave-uniform base + lane*16.
__device__ __forceinline__ void gl_lds16(const short* g, short* l) {
  __builtin_amdgcn_global_load_lds(
      (const __attribute__((address_space(1))) unsigned int*)(const void*)g,
      (__attribute__((address_space(3))) unsigned int*)(void*)l, 16, 0, 0);
}

__global__ __launch_bounds__(256) void fill_code_f32(float* __restrict__ out,
                                                     float code)
{
  out[blockIdx.x * 256 + threadIdx.x] = code;
}

// ---------------------------------------------------------------------------
// Weight pre-transpose + f32->bf16: dst[n*K + k] = bf16(src[k*N + n]).
// ---------------------------------------------------------------------------
__global__ __launch_bounds__(256) void prep_weights(
    const float* __restrict__ Wq, const float* __restrict__ Wk,
    const float* __restrict__ Wv, const float* __restrict__ Wo,
    const float* __restrict__ W1, const float* __restrict__ W2,
    short* __restrict__ Wqkvt, short* __restrict__ Wot,
    short* __restrict__ W1t,   short* __restrict__ W2t)
{
  int gw   = blockIdx.x * 4 + (threadIdx.x >> 6);
  int lane = threadIdx.x & 63;
  int l = gw / 6144;
  int g = gw % 6144;
  const float* src; short* dst; int K, N, gi;
  if (g < 2048) {                       // Wq,Wk,Wv,Wo  (512x512 each)
    int w = g >> 9; gi = g & 511; K = 512; N = 512;
    src = (w == 0 ? Wq : w == 1 ? Wk : w == 2 ? Wv : Wo) + l * 262144;
    dst = (w < 3) ? (Wqkvt + l * 786432 + w * 262144) : (Wot + l * 262144);
  } else if (g < 4096) {                // W1 (512 x 2048)
    gi = g - 2048; K = 512; N = 2048;
    src = W1 + l * 1048576; dst = W1t + l * 1048576;
  } else {                              // W2 (2048 x 512)
    gi = g - 4096; K = 2048; N = 512;
    src = W2 + l * 1048576; dst = W2t + l * 1048576;
  }
  int nb = N >> 6;
  int n  = (gi % nb) * 64 + lane;
  int k0 = (gi / nb) * 8;
  s16x8 v;
  #pragma unroll
  for (int i = 0; i < 8; i++) v[i] = f2bf(src[(size_t)(k0 + i) * N + n]);
  *(s16x8*)(dst + (size_t)n * K + k0) = v;
}

// f32 x -> f32 residual chain copy + bf16 GEMM operand
__global__ __launch_bounds__(256) void cast_kernel(const float* __restrict__ in,
                                                   float* __restrict__ outf,
                                                   short* __restrict__ outb)
{
  int i = blockIdx.x * 256 + threadIdx.x;
  float v = in[i];
  outf[i] = v;
  outb[i] = f2bf(v);
}

// Seed sumf for split-K atomic GEMMs.
__global__ __launch_bounds__(256) void init_oproj(float* __restrict__ sumf,
                                                  const float* __restrict__ bo)
{
  int i = blockIdx.x * 256 + threadIdx.x;
  sumf[i] += bo[i & 511];
}
__global__ __launch_bounds__(256) void init_ffn2(float* __restrict__ sumf,
                                                 const float* __restrict__ b2,
                                                 const short* __restrict__ xb)
{
  int i = blockIdx.x * 256 + threadIdx.x;
  sumf[i] = b2[i & 511] + bf2f(xb[i]);
}

// ---------------------------------------------------------------------------
// GEMM: C(M,N) = A(M,K) @ W, W pre-transposed Bt(N,K). bf16 MFMA.
// Tile TM x 128, BK=64 staged as TWO proven stride-32 half-tiles per barrier
// pair (layout per half identical to the harness-proven BK=32 form).
// Optional split-K (KS chunks of K, one block each, atomic f32 epilogue).
// Modes: 0=QKV scatter(+bias), 1=atomicAdd f32 into of (bias pre-seeded),
//        2=GELU->bf16(+bias)
// ---------------------------------------------------------------------------
template<int TM>
__global__ __launch_bounds__(256) void gemm_bt(
    const short* __restrict__ A, const short* __restrict__ Bt,
    int M, int N, int K, int KS, int mode,
    const float* __restrict__ bq, const float* __restrict__ bk,
    const float* __restrict__ bv,
    short* __restrict__ oq, short* __restrict__ okk, short* __restrict__ ov,
    float* of)
{
  __shared__ short As[2][TM * 32];     // two K-halves, proven layout each
  __shared__ short Bs[2][128 * 32];
  constexpr int MT = TM / 32;          // 16-row tiles per wave (4 or 2)
  const int tid  = threadIdx.x;
  const int lane = tid & 63;
  const int wid  = tid >> 6;
  const int lm   = lane & 15, quad = lane >> 4;
  const int nbn  = N >> 7;
  const int nb2  = (M / TM) * nbn;
  const int ks   = blockIdx.x / nb2;
  const int rem  = blockIdx.x % nb2;
  const int m0   = (rem / nbn) * TM;
  const int n0   = (rem % nbn) << 7;
  const int wm   = (wid & 1) * (TM / 2), wn = (wid >> 1) * 64;
  const int Kc   = K / KS;
  const int kbeg = ks * Kc;

  f32x4 acc[MT][4];
  #pragma unroll
  for (int i = 0; i < MT; i++)
    #pragma unroll
    for (int j = 0; j < 4; j++) acc[i][j] = (f32x4){0.f, 0.f, 0.f, 0.f};

  const short* Abase = A  + (size_t)m0 * K;
  const short* Bbase = Bt + (size_t)n0 * K;

  for (int k0 = kbeg; k0 < kbeg + Kc; k0 += 64) {
    __syncthreads();                     // prior iteration's LDS reads done
    #pragma unroll
    for (int half = 0; half < 2; half++) {
      const int kk = k0 + half * 32;
      #pragma unroll
      for (int j = 0; j < TM / 64; j++) {  // As half: TM*4 chunks of 16B
        int c = j * 256 + wid * 64 + lane;
        gl_lds16(Abase + (size_t)(c >> 2) * K + kk + (c & 3) * 8,
                 &As[half][(j * 256 + wid * 64) * 8]);
      }
      #pragma unroll
      for (int j = 0; j < 2; j++) {        // Bs half: 512 chunks
        int c = j * 256 + wid * 64 + lane;
        gl_lds16(Bbase + (size_t)(c >> 2) * K + kk + (c & 3) * 8,
                 &Bs[half][(j * 256 + wid * 64) * 8]);
      }
    }
    __syncthreads();                     // drains vmcnt -> tiles in LDS
    #pragma unroll
    for (int half = 0; half < 2; half++) {
      bf16x8 af[MT], bfr[4];
      #pragma unroll
      for (int t = 0; t < MT; t++)
        af[t] = *(const bf16x8*)&As[half][(wm + t * 16 + lm) * 32 + quad * 8];
      #pragma unroll
      for (int t = 0; t < 4; t++)
        bfr[t] = *(const bf16x8*)&Bs[half][(wn + t * 16 + lm) * 32 + quad * 8];
      #pragma unroll
      for (int mt = 0; mt < MT; mt++)
        #pragma unroll
        for (int nt = 0; nt < 4; nt++)
          acc[mt][nt] = mfma16(af[mt], bfr[nt], acc[mt][nt]);
    }
  }

  #pragma unroll
  for (int mt = 0; mt < MT; mt++) {
    int row = m0 + wm + mt * 16 + quad * 4;
    #pragma unroll
    for (int nt = 0; nt < 4; nt++) {
      int col = n0 + wn + nt * 16 + lm;
      f32x4 v = acc[mt][nt];
      if (mode == 0) {                       // QKV scatter, N=1536
        int which = col >> 9; int d = col & 511;
        int hh = d >> 6; int e = d & 63;
        const float* bias = which == 0 ? bq : which == 1 ? bk : bv;
        float bb = bias[d];
        #pragma unroll
        for (int r = 0; r < 4; r++) {
          int tok = row + r; int bI = tok >> 11, li = tok & 2047;
          float val = v[r] + bb;
          if (which == 0)
            oq [(((size_t)bI * NH + hh) * SEQ + li) * EH + e] = f2bf(val);
          else if (which == 1)
            okk[(((size_t)bI * NH + hh) * SEQ + li) * EH + e] = f2bf(val);
          else
            ov [(((size_t)bI * NH + hh) * EH + e) * SEQ + li] = f2bf(val);
        }
      } else if (mode == 1) {                // split-K atomic accumulate
        #pragma unroll
        for (int r = 0; r < 4; r++) {
          size_t idx = (size_t)(row + r) * N + col;
          unsafeAtomicAdd(&of[idx], v[r]);
        }
      } else {                               // GELU -> bf16
        float bb = bq[col];
        #pragma unroll
        for (int r = 0; r < 4; r++) {
          float x = v[r] + bb;
          float u = 0.7978845608f * (x + 0.044715f * x * x * x);
          float t = 1.f - 2.f / (1.f + __expf(2.f * u));   // tanh, safe
          size_t idx = (size_t)(row + r) * N + col;
          oq[idx] = f2bf(0.5f * x * (1.f + t));
        }
      }
    }
  }
}

// ---------------------------------------------------------------------------
// Flash attention v6 (harness-proven): v5 inner loop + 2-way key split.
// Fixed-bias softmax (linear in keys) -> partial (O,l) add exactly.
// ---------------------------------------------------------------------------
__global__ __launch_bounds__(256) void attn_v6(
    const short* __restrict__ Q, const short* __restrict__ Kg,
    const short* __restrict__ Vt,
    const float* __restrict__ tau, const float* __restrict__ delta,
    float* __restrict__ opart, float* __restrict__ lpart)
{
  __shared__ short Ks[64 * 72];       // [key][e]
  __shared__ short Vs[64 * 72];       // [e][key]
  __shared__ short Ps[4][16 * 72];    // per-wave P scratch [q][key]
  const int tid  = threadIdx.x;
  const int lane = tid & 63, wid = tid >> 6;
  const int lm = lane & 15, quad = lane >> 4;
  const int t    = blockIdx.x >> 1;   // tile id
  const int shlf = blockIdx.x & 1;    // key half
  const int qb = 31 - (t & 31);       // reversed: big-work blocks first
  const int h  = (t >> 5) & 7;
  const int b  = t >> 8;
  const int q0 = qb * 64;
  const int qw = q0 + wid * 16;
  const size_t bhq = ((size_t)b * NH + h) * SEQ;
  const short* kbase = Kg + bhq * EH;
  const short* vbase = Vt + ((size_t)b * NH + h) * (size_t)(EH * SEQ);

  const int h0  = (qb + 2) >> 1;      // ceil((qb+1)/2)
  const int kb0 = shlf ? h0 : 0;
  const int kb1 = shlf ? (qb + 1) : h0;

  bf16x8 qf0 = *(const bf16x8*)(Q + (bhq + qw + lm) * EH + quad * 8);
  bf16x8 qf1 = *(const bf16x8*)(Q + (bhq + qw + lm) * EH + 32 + quad * 8);

  const float st2 = 0.125f * LOG2E * tau[b];
  f32x4 O[4];
  #pragma unroll
  for (int i = 0; i < 4; i++) O[i] = (f32x4){0.f, 0.f, 0.f, 0.f};
  float lr[4] = {0.f, 0.f, 0.f, 0.f};   // per-lane partial row sums

  const int c0 = tid, c1 = tid + 256;      // 512 chunks of 8 shorts per tile
  const int r0 = c0 >> 3, ch0 = (c0 & 7) * 8;
  const int r1 = c1 >> 3, ch1 = (c1 & 7) * 8;

  for (int kb = kb0; kb < kb1; kb++) {
    const int s0 = kb << 6;
    s16x8 ka = *(const s16x8*)(kbase + (size_t)(s0 + r0) * EH + ch0);
    s16x8 kb_ = *(const s16x8*)(kbase + (size_t)(s0 + r1) * EH + ch1);
    s16x8 va = *(const s16x8*)(vbase + (size_t)r0 * SEQ + s0 + ch0);
    s16x8 vb = *(const s16x8*)(vbase + (size_t)r1 * SEQ + s0 + ch1);
    __syncthreads();                  // prior iteration's LDS reads done
    *(s16x8*)&Ks[r0 * 72 + ch0] = ka;
    *(s16x8*)&Ks[r1 * 72 + ch1] = kb_;
    *(s16x8*)&Vs[r0 * 72 + ch0] = va;
    *(s16x8*)&Vs[r1 * 72 + ch1] = vb;
    __syncthreads();

    // QK^T: 16 q x 64 keys
    f32x4 S[4];
    #pragma unroll
    for (int nt = 0; nt < 4; nt++) {
      S[nt] = (f32x4){0.f, 0.f, 0.f, 0.f};
      S[nt] = mfma16(qf0, *(const bf16x8*)&Ks[(nt*16 + lm) * 72 + quad * 8], S[nt]);
      S[nt] = mfma16(qf1, *(const bf16x8*)&Ks[(nt*16 + lm) * 72 + 32 + quad * 8], S[nt]);
    }
    float dl[4];
    #pragma unroll
    for (int nt = 0; nt < 4; nt++)    // delta in log2 domain, minus fixed M=8
      dl[nt] = fmaf(0.125f * LOG2E, delta[(size_t)b * SEQ + s0 + nt * 16 + lm],
                    -8.f);

    const bool diag = (kb == qb);
    #pragma unroll
    for (int r = 0; r < 4; r++) {
      float sc[4];
      #pragma unroll
      for (int nt = 0; nt < 4; nt++) sc[nt] = fmaf(st2, S[nt][r], dl[nt]);
      if (diag) {
        int rowq = qw + quad * 4 + r;
        #pragma unroll
        for (int nt = 0; nt < 4; nt++)
          if (s0 + nt * 16 + lm > rowq) sc[nt] = -__builtin_inff();
      }
      float p0 = exp2f(sc[0]), p1 = exp2f(sc[1]);
      float p2 = exp2f(sc[2]), p3 = exp2f(sc[3]);
      lr[r] += (p0 + p1) + (p2 + p3);
      short* pr = &Ps[wid][(quad * 4 + r) * 72];
      pr[lm]      = f2bf(p0);
      pr[16 + lm] = f2bf(p1);
      pr[32 + lm] = f2bf(p2);
      pr[48 + lm] = f2bf(p3);
    }

    // PV: P (16x64, per-wave LDS) @ V (64 keys x 64 e)
    bf16x8 pf0 = *(const bf16x8*)&Ps[wid][lm * 72 + quad * 8];
    bf16x8 pf1 = *(const bf16x8*)&Ps[wid][lm * 72 + 32 + quad * 8];
    #pragma unroll
    for (int et = 0; et < 4; et++) {
      O[et] = mfma16(pf0, *(const bf16x8*)&Vs[(et*16 + lm) * 72 + quad * 8], O[et]);
      O[et] = mfma16(pf1, *(const bf16x8*)&Vs[(et*16 + lm) * 72 + 32 + quad * 8], O[et]);
    }
  }

  // Reduce lr across the 16 lanes of each row group (once).
  #pragma unroll
  for (int r = 0; r < 4; r++) {
    float s = lr[r];
    #pragma unroll
    for (int off = 1; off < 16; off <<= 1) s += __shfl_xor(s, off);
    lr[r] = s;
  }

  // Write f32 partials: O to opart[slot], l to lpart[slot].
  const int slot = ((t << 1) | shlf);
  float* ob = opart + (size_t)slot * 4096;
  float* lb = lpart + (size_t)slot * 64;
  #pragma unroll
  for (int r = 0; r < 4; r++) {
    int qloc = wid * 16 + quad * 4 + r;
    #pragma unroll
    for (int et = 0; et < 4; et++)
      ob[qloc * 64 + et * 16 + lm] = O[et][r];
    if (lm == 0) lb[qloc] = lr[r];
  }
}

// Combine the 2 key-half partials, normalize, write bf16 at16 (B*L, D).
__global__ __launch_bounds__(256) void attn_reduce(
    const float* __restrict__ opart, const float* __restrict__ lpart,
    short* __restrict__ Oa)
{
  const int t = blockIdx.x;           // tile id (matches attn_v6 mapping)
  const int qb = 31 - (t & 31);
  const int h  = (t >> 5) & 7;
  const int b  = t >> 8;
  const int q0 = qb * 64;
  const float* o0 = opart + (size_t)(t * 2 + 0) * 4096;
  const float* o1 = opart + (size_t)(t * 2 + 1) * 4096;
  const float* l0 = lpart + (size_t)(t * 2 + 0) * 64;
  const float* l1 = lpart + (size_t)(t * 2 + 1) * 64;
  #pragma unroll
  for (int i = 0; i < 16; i++) {
    int idx = i * 256 + threadIdx.x;
    int q = idx >> 6, e = idx & 63;
    float l = l0[q] + l1[q];
    float o = o0[idx] + o1[idx];
    Oa[((size_t)b * SEQ + q0 + q) * DM + h * EH + e] = f2bf(o / l);
  }
}

// ---------------------------------------------------------------------------
// LayerNorm over D=512. One wave per row. f32 in; optional f32 out (may be
// in-place) + optional bf16 out.
// ---------------------------------------------------------------------------
__global__ __launch_bounds__(256) void ln_kernel(
    const float* in, const float* __restrict__ g, const float* __restrict__ bb,
    float* outf, short* outb)
{
  int row  = blockIdx.x * 4 + (threadIdx.x >> 6);
  int lane = threadIdx.x & 63;
  const float* p = in + (size_t)row * DM;
  float v[8]; float s = 0.f, ss = 0.f;
  #pragma unroll
  for (int i = 0; i < 8; i++) {
    float x = p[lane + i * 64]; v[i] = x; s += x; ss += x * x;
  }
  #pragma unroll
  for (int off = 32; off > 0; off >>= 1) {
    s += __shfl_xor(s, off); ss += __shfl_xor(ss, off);
  }
  float mean = s * (1.f / DM);
  float var  = ss * (1.f / DM) - mean * mean;
  float rstd = rsqrtf(var + 1e-5f);
  #pragma unroll
  for (int i = 0; i < 8; i++) {
    int c = lane + i * 64;
    float y = (v[i] - mean) * rstd * g[c] + bb[c];
    if (outf) outf[(size_t)row * DM + c] = y;
    if (outb) outb[(size_t)row * DM + c] = f2bf(y);
  }
}

// ---------------------------------------------------------------------------
extern "C" void kernel_launch(void* const* d_in, const int* in_sizes, int n_in,
                              void* d_out, int out_size, void* d_ws, size_t ws_size,
                              hipStream_t stream)
{
  float* out = (float*)d_out;          // f32 output

  if (ws_size < (size_t)62918656) {    // 60 MB + safety
    fill_code_f32<<<2097152 / 256, 256, 0, stream>>>(
        out, 1200.f + (float)(ws_size >> 20));
    return;
  }

  const float* x    = (const float*)d_in[0];
  const float* tau  = (const float*)d_in[1];
  const float* del  = (const float*)d_in[2];
  const float* Wq = (const float*)d_in[4];
  const float* bq = (const float*)d_in[5];
  const float* Wk = (const float*)d_in[6];
  const float* bk = (const float*)d_in[7];
  const float* Wv = (const float*)d_in[8];
  const float* bv = (const float*)d_in[9];
  const float* Wo = (const float*)d_in[10];
  const float* bo = (const float*)d_in[11];
  const float* W1 = (const float*)d_in[12];
  const float* b1 = (const float*)d_in[13];
  const float* W2 = (const float*)d_in[14];
  const float* b2 = (const float*)d_in[15];
  const float* ln1g = (const float*)d_in[16];
  const float* ln1b = (const float*)d_in[17];
  const float* ln2g = (const float*)d_in[18];
  const float* ln2b = (const float*)d_in[19];
  const float* lnfg = (const float*)d_in[20];
  const float* lnfb = (const float*)d_in[21];

  char* ws = (char*)d_ws;
  float* sumf  = (float*)(ws + 0);          //  8 MB  fp32 residual chain (x)
  short* x16   = (short*)(ws + 8388608);    //  4 MB  bf16 x (GEMM A operand)
  short* xb16  = (short*)(ws + 12582912);   //  4 MB  LN1 out (xb)
  short* q16   = (short*)(ws + 16777216);   //  4 MB  (B,H,L,E)
  short* k16   = (short*)(ws + 20971520);   //  4 MB  (B,H,L,E)
  short* vt16  = (short*)(ws + 25165824);   //  4 MB  (B,H,E,L)
  short* at16  = (short*)(ws + 29360128);   //  4 MB  attention out (B*L, D)
  short* h16   = (short*)(ws + 33554432);   // 16 MB  FFN hidden
  short* Wqkvt = (short*)(ws + 50331648);   //  3 MB
  short* Wot   = (short*)(ws + 53477376);   //  1 MB
  short* W1t   = (short*)(ws + 54525952);   //  4 MB
  short* W2t   = (short*)(ws + 58720256);   //  4 MB  (total 60 MB)
  // Attention partials overlay regions that are dead during attention:
  float* opart = (float*)(ws + 33554432);   // 16 MB (h16 region), 1024x4096 f32
  float* lpart = (float*)(ws + 12582912);   // 256 KB (xb16 region), 1024x64 f32

  prep_weights<<<3072, 256, 0, stream>>>(Wq, Wk, Wv, Wo, W1, W2,
                                         Wqkvt, Wot, W1t, W2t);
  cast_kernel<<<NTOK * DM / 256, 256, 0, stream>>>(x, sumf, x16);

  for (int l = 0; l < 2; l++) {
    // QKV (N=1536, K=512, KS=1, mode 0)
    gemm_bt<128><<<32 * 12, 256, 0, stream>>>(x16, Wqkvt + l * 786432,
        NTOK, 3 * DM, DM, 1, 0,
        bq + l * DM, bk + l * DM, bv + l * DM,
        q16, k16, vt16, nullptr);
    attn_v6<<<2 * NBAT * NH * (SEQ / 64), 256, 0, stream>>>(
        q16, k16, vt16, tau, del, opart, lpart);
    attn_reduce<<<NBAT * NH * (SEQ / 64), 256, 0, stream>>>(
        opart, lpart, at16);
    // O-proj: seed sumf += bo, then split-K x4 atomic GEMM (N=512, K=512)
    init_oproj<<<NTOK * DM / 256, 256, 0, stream>>>(sumf, bo + l * DM);
    gemm_bt<64><<<64 * 4 * 4, 256, 0, stream>>>(at16, Wot + l * 262144,
        NTOK, DM, DM, 4, 1,
        nullptr, nullptr, nullptr,
        nullptr, nullptr, nullptr, sumf);
    ln_kernel<<<NTOK / 4, 256, 0, stream>>>(sumf, ln1g + l * DM, ln1b + l * DM,
                                            nullptr, xb16);
    // FFN1 + GELU (N=2048, K=512, KS=1, mode 2)
    gemm_bt<128><<<32 * 16, 256, 0, stream>>>(xb16, W1t + l * 1048576,
        NTOK, DFF, DM, 1, 2,
        b1 + l * DFF, nullptr, nullptr,
        h16, nullptr, nullptr, nullptr);
    // FFN2: seed sumf = b2 + xb, then split-K x4 atomic GEMM (N=512, K=2048)
    init_ffn2<<<NTOK * DM / 256, 256, 0, stream>>>(sumf, b2 + l * DM, xb16);
    gemm_bt<64><<<64 * 4 * 4, 256, 0, stream>>>(h16, W2t + l * 1048576,
        NTOK, DM, DFF, 4, 1,
        nullptr, nullptr, nullptr,
        nullptr, nullptr, nullptr, sumf);
    // LN2 -> sumf (in place) + x16 (bf16 x for next layer's QKV)
    ln_kernel<<<NTOK / 4, 256, 0, stream>>>(sumf, ln2g + l * DM, ln2b + l * DM,
                                            sumf, x16);
  }
  ln_kernel<<<NTOK / 4, 256, 0, stream>>>(sumf, lnfg, lnfb, out, nullptr);
}

// Round 13
// 455.523 us; speedup vs baseline: 1.1158x; 1.1158x over previous
//
#include <hip/hip_runtime.h>
#include <stdint.h>

// Problem constants (fixed-size problem)
#define DM   512
#define DFF  2048
#define NH   8
#define EH   64
#define SEQ  2048
#define NBAT 2
#define NTOK (NBAT*SEQ)   // 4096
#define LOG2E 1.44269504088896340736f

typedef __attribute__((ext_vector_type(8))) short  s16x8;
typedef __attribute__((ext_vector_type(8))) __bf16 bf16x8;
typedef __attribute__((ext_vector_type(4))) float  f32x4;

__device__ __forceinline__ short f2bf(float f) {
  union { float f; unsigned int i; } c; c.f = f;
  unsigned int x = c.i;
  x += 0x7fffu + ((x >> 16) & 1u);   // RNE
  return (short)(x >> 16);
}
__device__ __forceinline__ float bf2f(short u) {
  union { unsigned int i; float f; } c;
  c.i = ((unsigned int)(unsigned short)u) << 16;
  return c.f;
}
__device__ __forceinline__ f32x4 mfma16(bf16x8 a, bf16x8 b, f32x4 c) {
  return __builtin_amdgcn_mfma_f32_16x16x32_bf16(a, b, c, 0, 0, 0);
}
// Async global->LDS, 16B per lane. LDS dest = wave-uniform base + lane*16.
__device__ __forceinline__ void gl_lds16(const short* g, short* l) {
  __builtin_amdgcn_global_load_lds(
      (const __attribute__((address_space(1))) unsigned int*)(const void*)g,
      (__attribute__((address_space(3))) unsigned int*)(void*)l, 16, 0, 0);
}

__global__ __launch_bounds__(256) void fill_code_f32(float* __restrict__ out,
                                                     float code)
{
  out[blockIdx.x * 256 + threadIdx.x] = code;
}

// ---------------------------------------------------------------------------
// Weight pre-transpose + f32->bf16: dst[n*K + k] = bf16(src[k*N + n]).
// ---------------------------------------------------------------------------
__global__ __launch_bounds__(256) void prep_weights(
    const float* __restrict__ Wq, const float* __restrict__ Wk,
    const float* __restrict__ Wv, const float* __restrict__ Wo,
    const float* __restrict__ W1, const float* __restrict__ W2,
    short* __restrict__ Wqkvt, short* __restrict__ Wot,
    short* __restrict__ W1t,   short* __restrict__ W2t)
{
  int gw   = blockIdx.x * 4 + (threadIdx.x >> 6);
  int lane = threadIdx.x & 63;
  int l = gw / 6144;
  int g = gw % 6144;
  const float* src; short* dst; int K, N, gi;
  if (g < 2048) {                       // Wq,Wk,Wv,Wo  (512x512 each)
    int w = g >> 9; gi = g & 511; K = 512; N = 512;
    src = (w == 0 ? Wq : w == 1 ? Wk : w == 2 ? Wv : Wo) + l * 262144;
    dst = (w < 3) ? (Wqkvt + l * 786432 + w * 262144) : (Wot + l * 262144);
  } else if (g < 4096) {                // W1 (512 x 2048)
    gi = g - 2048; K = 512; N = 2048;
    src = W1 + l * 1048576; dst = W1t + l * 1048576;
  } else {                              // W2 (2048 x 512)
    gi = g - 4096; K = 2048; N = 512;
    src = W2 + l * 1048576; dst = W2t + l * 1048576;
  }
  int nb = N >> 6;
  int n  = (gi % nb) * 64 + lane;
  int k0 = (gi / nb) * 8;
  s16x8 v;
  #pragma unroll
  for (int i = 0; i < 8; i++) v[i] = f2bf(src[(size_t)(k0 + i) * N + n]);
  *(s16x8*)(dst + (size_t)n * K + k0) = v;
}

// f32 x -> f32 residual chain copy + bf16 GEMM operand
__global__ __launch_bounds__(256) void cast_kernel(const float* __restrict__ in,
                                                   float* __restrict__ outf,
                                                   short* __restrict__ outb)
{
  int i = blockIdx.x * 256 + threadIdx.x;
  float v = in[i];
  outf[i] = v;
  outb[i] = f2bf(v);
}

// ---------------------------------------------------------------------------
// GEMM: C(M,N) = A(M,K) @ W, W pre-transposed Bt(N,K). bf16 MFMA.
// Tile TM x 128, BK=32, 4 waves, single-buffer async gl_lds16 staging
// (harness-proven round-11 structure). Modes: 0=QKV scatter,
// 1=O-proj(+bias+f32 resid->f32), 2=GELU->bf16, 3=FFN2(+bias+bf16 resid->f32)
// ---------------------------------------------------------------------------
template<int TM>
__global__ __launch_bounds__(256) void gemm_bt(
    const short* __restrict__ A, const short* __restrict__ Bt,
    int M, int N, int K, int mode,
    const float* __restrict__ bq, const float* __restrict__ bk,
    const float* __restrict__ bv,
    short* __restrict__ oq, short* __restrict__ okk, short* __restrict__ ov,
    float* of, const float* rf, const short* __restrict__ rb)
{
  __shared__ short As[TM * 32];
  __shared__ short Bs[128 * 32];
  constexpr int MT = TM / 32;          // 16-row tiles per wave (4 or 2)
  const int tid  = threadIdx.x;
  const int lane = tid & 63;
  const int wid  = tid >> 6;
  const int lm   = lane & 15, quad = lane >> 4;
  const int nbn  = N >> 7;
  const int m0   = (blockIdx.x / nbn) * TM;
  const int n0   = (blockIdx.x % nbn) << 7;
  const int wm   = (wid & 1) * (TM / 2), wn = (wid >> 1) * 64;

  f32x4 acc[MT][4];
  #pragma unroll
  for (int i = 0; i < MT; i++)
    #pragma unroll
    for (int j = 0; j < 4; j++) acc[i][j] = (f32x4){0.f, 0.f, 0.f, 0.f};

  const short* Abase = A  + (size_t)m0 * K;
  const short* Bbase = Bt + (size_t)n0 * K;

  for (int k0 = 0; k0 < K; k0 += 32) {
    __syncthreads();                     // prior iteration's LDS reads done
    #pragma unroll
    for (int j = 0; j < TM / 64; j++) {  // As: TM*4 chunks of 16B
      int c = j * 256 + wid * 64 + lane;
      gl_lds16(Abase + (size_t)(c >> 2) * K + k0 + (c & 3) * 8,
               &As[(j * 256 + wid * 64) * 8]);
    }
    #pragma unroll
    for (int j = 0; j < 2; j++) {        // Bs: 512 chunks
      int c = j * 256 + wid * 64 + lane;
      gl_lds16(Bbase + (size_t)(c >> 2) * K + k0 + (c & 3) * 8,
               &Bs[(j * 256 + wid * 64) * 8]);
    }
    __syncthreads();                     // drains vmcnt -> tiles in LDS
    bf16x8 af[MT], bfr[4];
    #pragma unroll
    for (int t = 0; t < MT; t++)
      af[t] = *(const bf16x8*)&As[(wm + t * 16 + lm) * 32 + quad * 8];
    #pragma unroll
    for (int t = 0; t < 4; t++)
      bfr[t] = *(const bf16x8*)&Bs[(wn + t * 16 + lm) * 32 + quad * 8];
    #pragma unroll
    for (int mt = 0; mt < MT; mt++)
      #pragma unroll
      for (int nt = 0; nt < 4; nt++)
        acc[mt][nt] = mfma16(af[mt], bfr[nt], acc[mt][nt]);
  }

  #pragma unroll
  for (int mt = 0; mt < MT; mt++) {
    int row = m0 + wm + mt * 16 + quad * 4;
    #pragma unroll
    for (int nt = 0; nt < 4; nt++) {
      int col = n0 + wn + nt * 16 + lm;
      f32x4 v = acc[mt][nt];
      if (mode == 0) {                       // QKV scatter, N=1536
        int which = col >> 9; int d = col & 511;
        int hh = d >> 6; int e = d & 63;
        const float* bias = which == 0 ? bq : which == 1 ? bk : bv;
        float bb = bias[d];
        #pragma unroll
        for (int r = 0; r < 4; r++) {
          int tok = row + r; int bI = tok >> 11, li = tok & 2047;
          float val = v[r] + bb;
          if (which == 0)
            oq [(((size_t)bI * NH + hh) * SEQ + li) * EH + e] = f2bf(val);
          else if (which == 1)
            okk[(((size_t)bI * NH + hh) * SEQ + li) * EH + e] = f2bf(val);
          else
            ov [(((size_t)bI * NH + hh) * EH + e) * SEQ + li] = f2bf(val);
        }
      } else if (mode == 1) {                // O-proj: f32 out = v+b+resid_f32
        float bb = bq[col];
        #pragma unroll
        for (int r = 0; r < 4; r++) {
          size_t idx = (size_t)(row + r) * N + col;
          of[idx] = v[r] + bb + rf[idx];
        }
      } else if (mode == 2) {                // GELU -> bf16
        float bb = bq[col];
        #pragma unroll
        for (int r = 0; r < 4; r++) {
          float x = v[r] + bb;
          float u = 0.7978845608f * (x + 0.044715f * x * x * x);
          float t = 1.f - 2.f / (1.f + __expf(2.f * u));   // tanh, safe
          size_t idx = (size_t)(row + r) * N + col;
          oq[idx] = f2bf(0.5f * x * (1.f + t));
        }
      } else {                               // FFN2: f32 out = v+b+resid_bf16
        float bb = bq[col];
        #pragma unroll
        for (int r = 0; r < 4; r++) {
          size_t idx = (size_t)(row + r) * N + col;
          of[idx] = v[r] + bb + bf2f(rb[idx]);
        }
      }
    }
  }
}

// ---------------------------------------------------------------------------
// Flash attention v6 (harness-proven): v5 inner loop + 2-way key split.
// Fixed-bias softmax (linear in keys) -> partial (O,l) add exactly.
// ---------------------------------------------------------------------------
__global__ __launch_bounds__(256) void attn_v6(
    const short* __restrict__ Q, const short* __restrict__ Kg,
    const short* __restrict__ Vt,
    const float* __restrict__ tau, const float* __restrict__ delta,
    float* __restrict__ opart, float* __restrict__ lpart)
{
  __shared__ short Ks[64 * 72];       // [key][e]
  __shared__ short Vs[64 * 72];       // [e][key]
  __shared__ short Ps[4][16 * 72];    // per-wave P scratch [q][key]
  const int tid  = threadIdx.x;
  const int lane = tid & 63, wid = tid >> 6;
  const int lm = lane & 15, quad = lane >> 4;
  const int t    = blockIdx.x >> 1;   // tile id
  const int shlf = blockIdx.x & 1;    // key half
  const int qb = 31 - (t & 31);       // reversed: big-work blocks first
  const int h  = (t >> 5) & 7;
  const int b  = t >> 8;
  const int q0 = qb * 64;
  const int qw = q0 + wid * 16;
  const size_t bhq = ((size_t)b * NH + h) * SEQ;
  const short* kbase = Kg + bhq * EH;
  const short* vbase = Vt + ((size_t)b * NH + h) * (size_t)(EH * SEQ);

  const int h0  = (qb + 2) >> 1;      // ceil((qb+1)/2)
  const int kb0 = shlf ? h0 : 0;
  const int kb1 = shlf ? (qb + 1) : h0;

  bf16x8 qf0 = *(const bf16x8*)(Q + (bhq + qw + lm) * EH + quad * 8);
  bf16x8 qf1 = *(const bf16x8*)(Q + (bhq + qw + lm) * EH + 32 + quad * 8);

  const float st2 = 0.125f * LOG2E * tau[b];
  f32x4 O[4];
  #pragma unroll
  for (int i = 0; i < 4; i++) O[i] = (f32x4){0.f, 0.f, 0.f, 0.f};
  float lr[4] = {0.f, 0.f, 0.f, 0.f};   // per-lane partial row sums

  const int c0 = tid, c1 = tid + 256;      // 512 chunks of 8 shorts per tile
  const int r0 = c0 >> 3, ch0 = (c0 & 7) * 8;
  const int r1 = c1 >> 3, ch1 = (c1 & 7) * 8;

  for (int kb = kb0; kb < kb1; kb++) {
    const int s0 = kb << 6;
    s16x8 ka = *(const s16x8*)(kbase + (size_t)(s0 + r0) * EH + ch0);
    s16x8 kb_ = *(const s16x8*)(kbase + (size_t)(s0 + r1) * EH + ch1);
    s16x8 va = *(const s16x8*)(vbase + (size_t)r0 * SEQ + s0 + ch0);
    s16x8 vb = *(const s16x8*)(vbase + (size_t)r1 * SEQ + s0 + ch1);
    __syncthreads();                  // prior iteration's LDS reads done
    *(s16x8*)&Ks[r0 * 72 + ch0] = ka;
    *(s16x8*)&Ks[r1 * 72 + ch1] = kb_;
    *(s16x8*)&Vs[r0 * 72 + ch0] = va;
    *(s16x8*)&Vs[r1 * 72 + ch1] = vb;
    __syncthreads();

    // QK^T: 16 q x 64 keys
    f32x4 S[4];
    #pragma unroll
    for (int nt = 0; nt < 4; nt++) {
      S[nt] = (f32x4){0.f, 0.f, 0.f, 0.f};
      S[nt] = mfma16(qf0, *(const bf16x8*)&Ks[(nt*16 + lm) * 72 + quad * 8], S[nt]);
      S[nt] = mfma16(qf1, *(const bf16x8*)&Ks[(nt*16 + lm) * 72 + 32 + quad * 8], S[nt]);
    }
    float dl[4];
    #pragma unroll
    for (int nt = 0; nt < 4; nt++)    // delta in log2 domain, minus fixed M=8
      dl[nt] = fmaf(0.125f * LOG2E, delta[(size_t)b * SEQ + s0 + nt * 16 + lm],
                    -8.f);

    const bool diag = (kb == qb);
    #pragma unroll
    for (int r = 0; r < 4; r++) {
      float sc[4];
      #pragma unroll
      for (int nt = 0; nt < 4; nt++) sc[nt] = fmaf(st2, S[nt][r], dl[nt]);
      if (diag) {
        int rowq = qw + quad * 4 + r;
        #pragma unroll
        for (int nt = 0; nt < 4; nt++)
          if (s0 + nt * 16 + lm > rowq) sc[nt] = -__builtin_inff();
      }
      float p0 = exp2f(sc[0]), p1 = exp2f(sc[1]);
      float p2 = exp2f(sc[2]), p3 = exp2f(sc[3]);
      lr[r] += (p0 + p1) + (p2 + p3);
      short* pr = &Ps[wid][(quad * 4 + r) * 72];
      pr[lm]      = f2bf(p0);
      pr[16 + lm] = f2bf(p1);
      pr[32 + lm] = f2bf(p2);
      pr[48 + lm] = f2bf(p3);
    }

    // PV: P (16x64, per-wave LDS) @ V (64 keys x 64 e)
    bf16x8 pf0 = *(const bf16x8*)&Ps[wid][lm * 72 + quad * 8];
    bf16x8 pf1 = *(const bf16x8*)&Ps[wid][lm * 72 + 32 + quad * 8];
    #pragma unroll
    for (int et = 0; et < 4; et++) {
      O[et] = mfma16(pf0, *(const bf16x8*)&Vs[(et*16 + lm) * 72 + quad * 8], O[et]);
      O[et] = mfma16(pf1, *(const bf16x8*)&Vs[(et*16 + lm) * 72 + 32 + quad * 8], O[et]);
    }
  }

  // Reduce lr across the 16 lanes of each row group (once).
  #pragma unroll
  for (int r = 0; r < 4; r++) {
    float s = lr[r];
    #pragma unroll
    for (int off = 1; off < 16; off <<= 1) s += __shfl_xor(s, off);
    lr[r] = s;
  }

  // Write f32 partials: O to opart[slot], l to lpart[slot].
  const int slot = ((t << 1) | shlf);
  float* ob = opart + (size_t)slot * 4096;
  float* lb = lpart + (size_t)slot * 64;
  #pragma unroll
  for (int r = 0; r < 4; r++) {
    int qloc = wid * 16 + quad * 4 + r;
    #pragma unroll
    for (int et = 0; et < 4; et++)
      ob[qloc * 64 + et * 16 + lm] = O[et][r];
    if (lm == 0) lb[qloc] = lr[r];
  }
}

// Combine the 2 key-half partials, normalize, write bf16 at16 (B*L, D).
__global__ __launch_bounds__(256) void attn_reduce(
    const float* __restrict__ opart, const float* __restrict__ lpart,
    short* __restrict__ Oa)
{
  const int t = blockIdx.x;           // tile id (matches attn_v6 mapping)
  const int qb = 31 - (t & 31);
  const int h  = (t >> 5) & 7;
  const int b  = t >> 8;
  const int q0 = qb * 64;
  const float* o0 = opart + (size_t)(t * 2 + 0) * 4096;
  const float* o1 = opart + (size_t)(t * 2 + 1) * 4096;
  const float* l0 = lpart + (size_t)(t * 2 + 0) * 64;
  const float* l1 = lpart + (size_t)(t * 2 + 1) * 64;
  #pragma unroll
  for (int i = 0; i < 16; i++) {
    int idx = i * 256 + threadIdx.x;
    int q = idx >> 6, e = idx & 63;
    float l = l0[q] + l1[q];
    float o = o0[idx] + o1[idx];
    Oa[((size_t)b * SEQ + q0 + q) * DM + h * EH + e] = f2bf(o / l);
  }
}

// ---------------------------------------------------------------------------
// LayerNorm over D=512. One wave per row. f32 in; optional f32 out (may be
// in-place) + optional bf16 out.
// ---------------------------------------------------------------------------
__global__ __launch_bounds__(256) void ln_kernel(
    const float* in, const float* __restrict__ g, const float* __restrict__ bb,
    float* outf, short* outb)
{
  int row  = blockIdx.x * 4 + (threadIdx.x >> 6);
  int lane = threadIdx.x & 63;
  const float* p = in + (size_t)row * DM;
  float v[8]; float s = 0.f, ss = 0.f;
  #pragma unroll
  for (int i = 0; i < 8; i++) {
    float x = p[lane + i * 64]; v[i] = x; s += x; ss += x * x;
  }
  #pragma unroll
  for (int off = 32; off > 0; off >>= 1) {
    s += __shfl_xor(s, off); ss += __shfl_xor(ss, off);
  }
  float mean = s * (1.f / DM);
  float var  = ss * (1.f / DM) - mean * mean;
  float rstd = rsqrtf(var + 1e-5f);
  #pragma unroll
  for (int i = 0; i < 8; i++) {
    int c = lane + i * 64;
    float y = (v[i] - mean) * rstd * g[c] + bb[c];
    if (outf) outf[(size_t)row * DM + c] = y;
    if (outb) outb[(size_t)row * DM + c] = f2bf(y);
  }
}

// ---------------------------------------------------------------------------
extern "C" void kernel_launch(void* const* d_in, const int* in_sizes, int n_in,
                              void* d_out, int out_size, void* d_ws, size_t ws_size,
                              hipStream_t stream)
{
  float* out = (float*)d_out;          // f32 output

  if (ws_size < (size_t)62918656) {    // 60 MB + safety
    fill_code_f32<<<2097152 / 256, 256, 0, stream>>>(
        out, 1200.f + (float)(ws_size >> 20));
    return;
  }

  const float* x    = (const float*)d_in[0];
  const float* tau  = (const float*)d_in[1];
  const float* del  = (const float*)d_in[2];
  const float* Wq = (const float*)d_in[4];
  const float* bq = (const float*)d_in[5];
  const float* Wk = (const float*)d_in[6];
  const float* bk = (const float*)d_in[7];
  const float* Wv = (const float*)d_in[8];
  const float* bv = (const float*)d_in[9];
  const float* Wo = (const float*)d_in[10];
  const float* bo = (const float*)d_in[11];
  const float* W1 = (const float*)d_in[12];
  const float* b1 = (const float*)d_in[13];
  const float* W2 = (const float*)d_in[14];
  const float* b2 = (const float*)d_in[15];
  const float* ln1g = (const float*)d_in[16];
  const float* ln1b = (const float*)d_in[17];
  const float* ln2g = (const float*)d_in[18];
  const float* ln2b = (const float*)d_in[19];
  const float* lnfg = (const float*)d_in[20];
  const float* lnfb = (const float*)d_in[21];

  char* ws = (char*)d_ws;
  float* sumf  = (float*)(ws + 0);          //  8 MB  fp32 residual chain (x)
  short* x16   = (short*)(ws + 8388608);    //  4 MB  bf16 x (GEMM A operand)
  short* xb16  = (short*)(ws + 12582912);   //  4 MB  LN1 out (xb)
  short* q16   = (short*)(ws + 16777216);   //  4 MB  (B,H,L,E)
  short* k16   = (short*)(ws + 20971520);   //  4 MB  (B,H,L,E)
  short* vt16  = (short*)(ws + 25165824);   //  4 MB  (B,H,E,L)
  short* at16  = (short*)(ws + 29360128);   //  4 MB  attention out (B*L, D)
  short* h16   = (short*)(ws + 33554432);   // 16 MB  FFN hidden
  short* Wqkvt = (short*)(ws + 50331648);   //  3 MB
  short* Wot   = (short*)(ws + 53477376);   //  1 MB
  short* W1t   = (short*)(ws + 54525952);   //  4 MB
  short* W2t   = (short*)(ws + 58720256);   //  4 MB  (total 60 MB)
  // Attention partials overlay regions that are dead during attention:
  float* opart = (float*)(ws + 33554432);   // 16 MB (h16 region), 1024x4096 f32
  float* lpart = (float*)(ws + 12582912);   // 256 KB (xb16 region), 1024x64 f32

  prep_weights<<<3072, 256, 0, stream>>>(Wq, Wk, Wv, Wo, W1, W2,
                                         Wqkvt, Wot, W1t, W2t);
  cast_kernel<<<NTOK * DM / 256, 256, 0, stream>>>(x, sumf, x16);

  for (int l = 0; l < 2; l++) {
    // QKV (N=1536, K=512) -- TM=64: 768 blocks (3/CU) for latency hiding
    gemm_bt<64><<<64 * 12, 256, 0, stream>>>(x16, Wqkvt + l * 786432,
        NTOK, 3 * DM, DM, 0,
        bq + l * DM, bk + l * DM, bv + l * DM,
        q16, k16, vt16, nullptr, nullptr, nullptr);
    attn_v6<<<2 * NBAT * NH * (SEQ / 64), 256, 0, stream>>>(
        q16, k16, vt16, tau, del, opart, lpart);
    attn_reduce<<<NBAT * NH * (SEQ / 64), 256, 0, stream>>>(
        opart, lpart, at16);
    gemm_bt<64><<<64 * 4, 256, 0, stream>>>(at16, Wot + l * 262144,
        NTOK, DM, DM, 1,
        bo + l * DM, nullptr, nullptr,
        nullptr, nullptr, nullptr, sumf, sumf, nullptr);
    ln_kernel<<<NTOK / 4, 256, 0, stream>>>(sumf, ln1g + l * DM, ln1b + l * DM,
                                            nullptr, xb16);
    // FFN1 + GELU (N=2048, K=512) -- TM=64: 1024 blocks (4/CU)
    gemm_bt<64><<<64 * 16, 256, 0, stream>>>(xb16, W1t + l * 1048576,
        NTOK, DFF, DM, 2,
        b1 + l * DFF, nullptr, nullptr,
        h16, nullptr, nullptr, nullptr, nullptr, nullptr);
    gemm_bt<64><<<64 * 4, 256, 0, stream>>>(h16, W2t + l * 1048576,
        NTOK, DM, DFF, 3,
        b2 + l * DM, nullptr, nullptr,
        nullptr, nullptr, nullptr, sumf, nullptr, xb16);
    ln_kernel<<<NTOK / 4, 256, 0, stream>>>(sumf, ln2g + l * DM, ln2b + l * DM,
                                            sumf, x16);
  }
  ln_kernel<<<NTOK / 4, 256, 0, stream>>>(sumf, lnfg, lnfb, out, nullptr);
}

// Round 14
// 441.049 us; speedup vs baseline: 1.1524x; 1.0328x over previous
//
#include <hip/hip_runtime.h>
#include <stdint.h>

// Problem constants (fixed-size problem)
#define DM   512
#define DFF  2048
#define NH   8
#define EH   64
#define SEQ  2048
#define NBAT 2
#define NTOK (NBAT*SEQ)   // 4096
#define LOG2E 1.44269504088896340736f

typedef __attribute__((ext_vector_type(8))) short  s16x8;
typedef __attribute__((ext_vector_type(8))) __bf16 bf16x8;
typedef __attribute__((ext_vector_type(4))) float  f32x4;

__device__ __forceinline__ short f2bf(float f) {
  union { float f; unsigned int i; } c; c.f = f;
  unsigned int x = c.i;
  x += 0x7fffu + ((x >> 16) & 1u);   // RNE
  return (short)(x >> 16);
}
__device__ __forceinline__ float bf2f(short u) {
  union { unsigned int i; float f; } c;
  c.i = ((unsigned int)(unsigned short)u) << 16;
  return c.f;
}
__device__ __forceinline__ f32x4 mfma16(bf16x8 a, bf16x8 b, f32x4 c) {
  return __builtin_amdgcn_mfma_f32_16x16x32_bf16(a, b, c, 0, 0, 0);
}
// Async global->LDS, 16B per lane. LDS dest = wave-uniform base + lane*16.
__device__ __forceinline__ void gl_lds16(const short* g, short* l) {
  __builtin_amdgcn_global_load_lds(
      (const __attribute__((address_space(1))) unsigned int*)(const void*)g,
      (__attribute__((address_space(3))) unsigned int*)(void*)l, 16, 0, 0);
}

__global__ __launch_bounds__(256) void fill_code_f32(float* __restrict__ out,
                                                     float code)
{
  out[blockIdx.x * 256 + threadIdx.x] = code;
}

// ---------------------------------------------------------------------------
// Weight pre-transpose + f32->bf16: dst[n*K + k] = bf16(src[k*N + n]).
// ---------------------------------------------------------------------------
__global__ __launch_bounds__(256) void prep_weights(
    const float* __restrict__ Wq, const float* __restrict__ Wk,
    const float* __restrict__ Wv, const float* __restrict__ Wo,
    const float* __restrict__ W1, const float* __restrict__ W2,
    short* __restrict__ Wqkvt, short* __restrict__ Wot,
    short* __restrict__ W1t,   short* __restrict__ W2t)
{
  int gw   = blockIdx.x * 4 + (threadIdx.x >> 6);
  int lane = threadIdx.x & 63;
  int l = gw / 6144;
  int g = gw % 6144;
  const float* src; short* dst; int K, N, gi;
  if (g < 2048) {                       // Wq,Wk,Wv,Wo  (512x512 each)
    int w = g >> 9; gi = g & 511; K = 512; N = 512;
    src = (w == 0 ? Wq : w == 1 ? Wk : w == 2 ? Wv : Wo) + l * 262144;
    dst = (w < 3) ? (Wqkvt + l * 786432 + w * 262144) : (Wot + l * 262144);
  } else if (g < 4096) {                // W1 (512 x 2048)
    gi = g - 2048; K = 512; N = 2048;
    src = W1 + l * 1048576; dst = W1t + l * 1048576;
  } else {                              // W2 (2048 x 512)
    gi = g - 4096; K = 2048; N = 512;
    src = W2 + l * 1048576; dst = W2t + l * 1048576;
  }
  int nb = N >> 6;
  int n  = (gi % nb) * 64 + lane;
  int k0 = (gi / nb) * 8;
  s16x8 v;
  #pragma unroll
  for (int i = 0; i < 8; i++) v[i] = f2bf(src[(size_t)(k0 + i) * N + n]);
  *(s16x8*)(dst + (size_t)n * K + k0) = v;
}

// f32 x -> f32 residual chain copy + bf16 GEMM operand
__global__ __launch_bounds__(256) void cast_kernel(const float* __restrict__ in,
                                                   float* __restrict__ outf,
                                                   short* __restrict__ outb)
{
  int i = blockIdx.x * 256 + threadIdx.x;
  float v = in[i];
  outf[i] = v;
  outb[i] = f2bf(v);
}

// ---------------------------------------------------------------------------
// GEMM: C(M,N) = A(M,K) @ W, W pre-transposed Bt(N,K). bf16 MFMA.
// Tile TM x 128, BK=32, 4 waves, single-buffer async gl_lds16 staging
// (harness-proven round-11 structure). Modes: 0=QKV scatter,
// 1=O-proj(+bias+f32 resid->f32), 2=GELU->bf16, 3=FFN2(+bias+bf16 resid->f32)
// ---------------------------------------------------------------------------
template<int TM>
__global__ __launch_bounds__(256) void gemm_bt(
    const short* __restrict__ A, const short* __restrict__ Bt,
    int M, int N, int K, int mode,
    const float* __restrict__ bq, const float* __restrict__ bk,
    const float* __restrict__ bv,
    short* __restrict__ oq, short* __restrict__ okk, short* __restrict__ ov,
    float* of, const float* rf, const short* __restrict__ rb)
{
  __shared__ short As[TM * 32];
  __shared__ short Bs[128 * 32];
  constexpr int MT = TM / 32;          // 16-row tiles per wave (4 or 2)
  const int tid  = threadIdx.x;
  const int lane = tid & 63;
  const int wid  = tid >> 6;
  const int lm   = lane & 15, quad = lane >> 4;
  const int nbn  = N >> 7;
  const int m0   = (blockIdx.x / nbn) * TM;
  const int n0   = (blockIdx.x % nbn) << 7;
  const int wm   = (wid & 1) * (TM / 2), wn = (wid >> 1) * 64;

  f32x4 acc[MT][4];
  #pragma unroll
  for (int i = 0; i < MT; i++)
    #pragma unroll
    for (int j = 0; j < 4; j++) acc[i][j] = (f32x4){0.f, 0.f, 0.f, 0.f};

  const short* Abase = A  + (size_t)m0 * K;
  const short* Bbase = Bt + (size_t)n0 * K;

  for (int k0 = 0; k0 < K; k0 += 32) {
    __syncthreads();                     // prior iteration's LDS reads done
    #pragma unroll
    for (int j = 0; j < TM / 64; j++) {  // As: TM*4 chunks of 16B
      int c = j * 256 + wid * 64 + lane;
      gl_lds16(Abase + (size_t)(c >> 2) * K + k0 + (c & 3) * 8,
               &As[(j * 256 + wid * 64) * 8]);
    }
    #pragma unroll
    for (int j = 0; j < 2; j++) {        // Bs: 512 chunks
      int c = j * 256 + wid * 64 + lane;
      gl_lds16(Bbase + (size_t)(c >> 2) * K + k0 + (c & 3) * 8,
               &Bs[(j * 256 + wid * 64) * 8]);
    }
    __syncthreads();                     // drains vmcnt -> tiles in LDS
    bf16x8 af[MT], bfr[4];
    #pragma unroll
    for (int t = 0; t < MT; t++)
      af[t] = *(const bf16x8*)&As[(wm + t * 16 + lm) * 32 + quad * 8];
    #pragma unroll
    for (int t = 0; t < 4; t++)
      bfr[t] = *(const bf16x8*)&Bs[(wn + t * 16 + lm) * 32 + quad * 8];
    #pragma unroll
    for (int mt = 0; mt < MT; mt++)
      #pragma unroll
      for (int nt = 0; nt < 4; nt++)
        acc[mt][nt] = mfma16(af[mt], bfr[nt], acc[mt][nt]);
  }

  #pragma unroll
  for (int mt = 0; mt < MT; mt++) {
    int row = m0 + wm + mt * 16 + quad * 4;
    #pragma unroll
    for (int nt = 0; nt < 4; nt++) {
      int col = n0 + wn + nt * 16 + lm;
      f32x4 v = acc[mt][nt];
      if (mode == 0) {                       // QKV scatter, N=1536
        int which = col >> 9; int d = col & 511;
        int hh = d >> 6; int e = d & 63;
        const float* bias = which == 0 ? bq : which == 1 ? bk : bv;
        float bb = bias[d];
        #pragma unroll
        for (int r = 0; r < 4; r++) {
          int tok = row + r; int bI = tok >> 11, li = tok & 2047;
          float val = v[r] + bb;
          if (which == 0)
            oq [(((size_t)bI * NH + hh) * SEQ + li) * EH + e] = f2bf(val);
          else if (which == 1)
            okk[(((size_t)bI * NH + hh) * SEQ + li) * EH + e] = f2bf(val);
          else
            ov [(((size_t)bI * NH + hh) * EH + e) * SEQ + li] = f2bf(val);
        }
      } else if (mode == 1) {                // O-proj: f32 out = v+b+resid_f32
        float bb = bq[col];
        #pragma unroll
        for (int r = 0; r < 4; r++) {
          size_t idx = (size_t)(row + r) * N + col;
          of[idx] = v[r] + bb + rf[idx];
        }
      } else if (mode == 2) {                // GELU -> bf16
        float bb = bq[col];
        #pragma unroll
        for (int r = 0; r < 4; r++) {
          float x = v[r] + bb;
          float u = 0.7978845608f * (x + 0.044715f * x * x * x);
          float t = 1.f - 2.f / (1.f + __expf(2.f * u));   // tanh, safe
          size_t idx = (size_t)(row + r) * N + col;
          oq[idx] = f2bf(0.5f * x * (1.f + t));
        }
      } else {                               // FFN2: f32 out = v+b+resid_bf16
        float bb = bq[col];
        #pragma unroll
        for (int r = 0; r < 4; r++) {
          size_t idx = (size_t)(row + r) * N + col;
          of[idx] = v[r] + bb + bf2f(rb[idx]);
        }
      }
    }
  }
}

// ---------------------------------------------------------------------------
// Flash attention v7 = v6 proven inner loop + 4-WAY key split.
// Fixed-bias softmax is linear in keys -> partial (O,l) add exactly.
// O partials stored bf16 (halves footprint -> fits h16), l partials f32.
// Chunk c of tile t covers key-blocks [floor(nblk*c/4), floor(nblk*(c+1)/4)).
// ---------------------------------------------------------------------------
__global__ __launch_bounds__(256) void attn_v7(
    const short* __restrict__ Q, const short* __restrict__ Kg,
    const short* __restrict__ Vt,
    const float* __restrict__ tau, const float* __restrict__ delta,
    short* __restrict__ opart, float* __restrict__ lpart)
{
  __shared__ short Ks[64 * 72];       // [key][e]
  __shared__ short Vs[64 * 72];       // [e][key]
  __shared__ short Ps[4][16 * 72];    // per-wave P scratch [q][key]
  const int tid  = threadIdx.x;
  const int lane = tid & 63, wid = tid >> 6;
  const int lm = lane & 15, quad = lane >> 4;
  const int t    = blockIdx.x >> 2;   // tile id
  const int part = blockIdx.x & 3;    // key quarter
  const int qb = 31 - (t & 31);       // reversed: big-work blocks first
  const int h  = (t >> 5) & 7;
  const int b  = t >> 8;
  const int q0 = qb * 64;
  const int qw = q0 + wid * 16;
  const size_t bhq = ((size_t)b * NH + h) * SEQ;
  const short* kbase = Kg + bhq * EH;
  const short* vbase = Vt + ((size_t)b * NH + h) * (size_t)(EH * SEQ);

  const int nblk = qb + 1;
  const int kb0 = (nblk * part) >> 2;
  const int kb1 = (nblk * (part + 1)) >> 2;

  bf16x8 qf0 = *(const bf16x8*)(Q + (bhq + qw + lm) * EH + quad * 8);
  bf16x8 qf1 = *(const bf16x8*)(Q + (bhq + qw + lm) * EH + 32 + quad * 8);

  const float st2 = 0.125f * LOG2E * tau[b];
  f32x4 O[4];
  #pragma unroll
  for (int i = 0; i < 4; i++) O[i] = (f32x4){0.f, 0.f, 0.f, 0.f};
  float lr[4] = {0.f, 0.f, 0.f, 0.f};   // per-lane partial row sums

  const int c0 = tid, c1 = tid + 256;      // 512 chunks of 8 shorts per tile
  const int r0 = c0 >> 3, ch0 = (c0 & 7) * 8;
  const int r1 = c1 >> 3, ch1 = (c1 & 7) * 8;

  for (int kb = kb0; kb < kb1; kb++) {
    const int s0 = kb << 6;
    s16x8 ka = *(const s16x8*)(kbase + (size_t)(s0 + r0) * EH + ch0);
    s16x8 kb_ = *(const s16x8*)(kbase + (size_t)(s0 + r1) * EH + ch1);
    s16x8 va = *(const s16x8*)(vbase + (size_t)r0 * SEQ + s0 + ch0);
    s16x8 vb = *(const s16x8*)(vbase + (size_t)r1 * SEQ + s0 + ch1);
    __syncthreads();                  // prior iteration's LDS reads done
    *(s16x8*)&Ks[r0 * 72 + ch0] = ka;
    *(s16x8*)&Ks[r1 * 72 + ch1] = kb_;
    *(s16x8*)&Vs[r0 * 72 + ch0] = va;
    *(s16x8*)&Vs[r1 * 72 + ch1] = vb;
    __syncthreads();

    // QK^T: 16 q x 64 keys
    f32x4 S[4];
    #pragma unroll
    for (int nt = 0; nt < 4; nt++) {
      S[nt] = (f32x4){0.f, 0.f, 0.f, 0.f};
      S[nt] = mfma16(qf0, *(const bf16x8*)&Ks[(nt*16 + lm) * 72 + quad * 8], S[nt]);
      S[nt] = mfma16(qf1, *(const bf16x8*)&Ks[(nt*16 + lm) * 72 + 32 + quad * 8], S[nt]);
    }
    float dl[4];
    #pragma unroll
    for (int nt = 0; nt < 4; nt++)    // delta in log2 domain, minus fixed M=8
      dl[nt] = fmaf(0.125f * LOG2E, delta[(size_t)b * SEQ + s0 + nt * 16 + lm],
                    -8.f);

    const bool diag = (kb == qb);
    #pragma unroll
    for (int r = 0; r < 4; r++) {
      float sc[4];
      #pragma unroll
      for (int nt = 0; nt < 4; nt++) sc[nt] = fmaf(st2, S[nt][r], dl[nt]);
      if (diag) {
        int rowq = qw + quad * 4 + r;
        #pragma unroll
        for (int nt = 0; nt < 4; nt++)
          if (s0 + nt * 16 + lm > rowq) sc[nt] = -__builtin_inff();
      }
      float p0 = exp2f(sc[0]), p1 = exp2f(sc[1]);
      float p2 = exp2f(sc[2]), p3 = exp2f(sc[3]);
      lr[r] += (p0 + p1) + (p2 + p3);
      short* pr = &Ps[wid][(quad * 4 + r) * 72];
      pr[lm]      = f2bf(p0);
      pr[16 + lm] = f2bf(p1);
      pr[32 + lm] = f2bf(p2);
      pr[48 + lm] = f2bf(p3);
    }

    // PV: P (16x64, per-wave LDS) @ V (64 keys x 64 e)
    bf16x8 pf0 = *(const bf16x8*)&Ps[wid][lm * 72 + quad * 8];
    bf16x8 pf1 = *(const bf16x8*)&Ps[wid][lm * 72 + 32 + quad * 8];
    #pragma unroll
    for (int et = 0; et < 4; et++) {
      O[et] = mfma16(pf0, *(const bf16x8*)&Vs[(et*16 + lm) * 72 + quad * 8], O[et]);
      O[et] = mfma16(pf1, *(const bf16x8*)&Vs[(et*16 + lm) * 72 + 32 + quad * 8], O[et]);
    }
  }

  // Reduce lr across the 16 lanes of each row group (once).
  #pragma unroll
  for (int r = 0; r < 4; r++) {
    float s = lr[r];
    #pragma unroll
    for (int off = 1; off < 16; off <<= 1) s += __shfl_xor(s, off);
    lr[r] = s;
  }

  // Write partials: O (bf16) to opart[slot], l (f32) to lpart[slot].
  const int slot = ((t << 2) | part);
  short* ob = opart + (size_t)slot * 4096;
  float* lb = lpart + (size_t)slot * 64;
  #pragma unroll
  for (int r = 0; r < 4; r++) {
    int qloc = wid * 16 + quad * 4 + r;
    #pragma unroll
    for (int et = 0; et < 4; et++)
      ob[qloc * 64 + et * 16 + lm] = f2bf(O[et][r]);
    if (lm == 0) lb[qloc] = lr[r];
  }
}

// Combine the 4 key-quarter partials, normalize, write bf16 at16 (B*L, D).
__global__ __launch_bounds__(256) void attn_reduce(
    const short* __restrict__ opart, const float* __restrict__ lpart,
    short* __restrict__ Oa)
{
  const int t = blockIdx.x;           // tile id (matches attn_v7 mapping)
  const int qb = 31 - (t & 31);
  const int h  = (t >> 5) & 7;
  const int b  = t >> 8;
  const int q0 = qb * 64;
  #pragma unroll
  for (int i = 0; i < 16; i++) {
    int idx = i * 256 + threadIdx.x;
    int q = idx >> 6, e = idx & 63;
    float l = 0.f, o = 0.f;
    #pragma unroll
    for (int p = 0; p < 4; p++) {
      int slot = t * 4 + p;
      l += lpart[(size_t)slot * 64 + q];
      o += bf2f(opart[(size_t)slot * 4096 + idx]);
    }
    Oa[((size_t)b * SEQ + q0 + q) * DM + h * EH + e] = f2bf(o / l);
  }
}

// ---------------------------------------------------------------------------
// LayerNorm over D=512. One wave per row. f32 in; optional f32 out (may be
// in-place) + optional bf16 out.
// ---------------------------------------------------------------------------
__global__ __launch_bounds__(256) void ln_kernel(
    const float* in, const float* __restrict__ g, const float* __restrict__ bb,
    float* outf, short* outb)
{
  int row  = blockIdx.x * 4 + (threadIdx.x >> 6);
  int lane = threadIdx.x & 63;
  const float* p = in + (size_t)row * DM;
  float v[8]; float s = 0.f, ss = 0.f;
  #pragma unroll
  for (int i = 0; i < 8; i++) {
    float x = p[lane + i * 64]; v[i] = x; s += x; ss += x * x;
  }
  #pragma unroll
  for (int off = 32; off > 0; off >>= 1) {
    s += __shfl_xor(s, off); ss += __shfl_xor(ss, off);
  }
  float mean = s * (1.f / DM);
  float var  = ss * (1.f / DM) - mean * mean;
  float rstd = rsqrtf(var + 1e-5f);
  #pragma unroll
  for (int i = 0; i < 8; i++) {
    int c = lane + i * 64;
    float y = (v[i] - mean) * rstd * g[c] + bb[c];
    if (outf) outf[(size_t)row * DM + c] = y;
    if (outb) outb[(size_t)row * DM + c] = f2bf(y);
  }
}

// ---------------------------------------------------------------------------
extern "C" void kernel_launch(void* const* d_in, const int* in_sizes, int n_in,
                              void* d_out, int out_size, void* d_ws, size_t ws_size,
                              hipStream_t stream)
{
  float* out = (float*)d_out;          // f32 output

  if (ws_size < (size_t)62918656) {    // 60 MB + safety
    fill_code_f32<<<2097152 / 256, 256, 0, stream>>>(
        out, 1200.f + (float)(ws_size >> 20));
    return;
  }

  const float* x    = (const float*)d_in[0];
  const float* tau  = (const float*)d_in[1];
  const float* del  = (const float*)d_in[2];
  const float* Wq = (const float*)d_in[4];
  const float* bq = (const float*)d_in[5];
  const float* Wk = (const float*)d_in[6];
  const float* bk = (const float*)d_in[7];
  const float* Wv = (const float*)d_in[8];
  const float* bv = (const float*)d_in[9];
  const float* Wo = (const float*)d_in[10];
  const float* bo = (const float*)d_in[11];
  const float* W1 = (const float*)d_in[12];
  const float* b1 = (const float*)d_in[13];
  const float* W2 = (const float*)d_in[14];
  const float* b2 = (const float*)d_in[15];
  const float* ln1g = (const float*)d_in[16];
  const float* ln1b = (const float*)d_in[17];
  const float* ln2g = (const float*)d_in[18];
  const float* ln2b = (const float*)d_in[19];
  const float* lnfg = (const float*)d_in[20];
  const float* lnfb = (const float*)d_in[21];

  char* ws = (char*)d_ws;
  float* sumf  = (float*)(ws + 0);          //  8 MB  fp32 residual chain (x)
  short* x16   = (short*)(ws + 8388608);    //  4 MB  bf16 x (GEMM A operand)
  short* xb16  = (short*)(ws + 12582912);   //  4 MB  LN1 out (xb)
  short* q16   = (short*)(ws + 16777216);   //  4 MB  (B,H,L,E)
  short* k16   = (short*)(ws + 20971520);   //  4 MB  (B,H,L,E)
  short* vt16  = (short*)(ws + 25165824);   //  4 MB  (B,H,E,L)
  short* at16  = (short*)(ws + 29360128);   //  4 MB  attention out (B*L, D)
  short* h16   = (short*)(ws + 33554432);   // 16 MB  FFN hidden
  short* Wqkvt = (short*)(ws + 50331648);   //  3 MB
  short* Wot   = (short*)(ws + 53477376);   //  1 MB
  short* W1t   = (short*)(ws + 54525952);   //  4 MB
  short* W2t   = (short*)(ws + 58720256);   //  4 MB  (total 60 MB)
  // Attention partials overlay regions dead during attention:
  short* opart = (short*)(ws + 33554432);   // 16 MB (h16 region), 2048x4096 bf16
  float* lpart = (float*)(ws + 12582912);   // 512 KB (xb16 region), 2048x64 f32

  prep_weights<<<3072, 256, 0, stream>>>(Wq, Wk, Wv, Wo, W1, W2,
                                         Wqkvt, Wot, W1t, W2t);
  cast_kernel<<<NTOK * DM / 256, 256, 0, stream>>>(x, sumf, x16);

  for (int l = 0; l < 2; l++) {
    // QKV (N=1536, K=512) -- TM=64: 768 blocks (3/CU)
    gemm_bt<64><<<64 * 12, 256, 0, stream>>>(x16, Wqkvt + l * 786432,
        NTOK, 3 * DM, DM, 0,
        bq + l * DM, bk + l * DM, bv + l * DM,
        q16, k16, vt16, nullptr, nullptr, nullptr);
    attn_v7<<<4 * NBAT * NH * (SEQ / 64), 256, 0, stream>>>(
        q16, k16, vt16, tau, del, opart, lpart);
    attn_reduce<<<NBAT * NH * (SEQ / 64), 256, 0, stream>>>(
        opart, lpart, at16);
    gemm_bt<64><<<64 * 4, 256, 0, stream>>>(at16, Wot + l * 262144,
        NTOK, DM, DM, 1,
        bo + l * DM, nullptr, nullptr,
        nullptr, nullptr, nullptr, sumf, sumf, nullptr);
    ln_kernel<<<NTOK / 4, 256, 0, stream>>>(sumf, ln1g + l * DM, ln1b + l * DM,
                                            nullptr, xb16);
    // FFN1 + GELU (N=2048, K=512) -- TM=64: 1024 blocks (4/CU)
    gemm_bt<64><<<64 * 16, 256, 0, stream>>>(xb16, W1t + l * 1048576,
        NTOK, DFF, DM, 2,
        b1 + l * DFF, nullptr, nullptr,
        h16, nullptr, nullptr, nullptr, nullptr, nullptr);
    gemm_bt<64><<<64 * 4, 256, 0, stream>>>(h16, W2t + l * 1048576,
        NTOK, DM, DFF, 3,
        b2 + l * DM, nullptr, nullptr,
        nullptr, nullptr, nullptr, sumf, nullptr, xb16);
    ln_kernel<<<NTOK / 4, 256, 0, stream>>>(sumf, ln2g + l * DM, ln2b + l * DM,
                                            sumf, x16);
  }
  ln_kernel<<<NTOK / 4, 256, 0, stream>>>(sumf, lnfg, lnfb, out, nullptr);
}

// Round 15
// 437.259 us; speedup vs baseline: 1.1624x; 1.0087x over previous
//
#include <hip/hip_runtime.h>
#include <stdint.h>

// Problem constants (fixed-size problem)
#define DM   512
#define DFF  2048
#define NH   8
#define EH   64
#define SEQ  2048
#define NBAT 2
#define NTOK (NBAT*SEQ)   // 4096
#define LOG2E 1.44269504088896340736f

typedef __attribute__((ext_vector_type(8))) short  s16x8;
typedef __attribute__((ext_vector_type(8))) __bf16 bf16x8;
typedef __attribute__((ext_vector_type(4))) float  f32x4;

__device__ __forceinline__ short f2bf(float f) {
  union { float f; unsigned int i; } c; c.f = f;
  unsigned int x = c.i;
  x += 0x7fffu + ((x >> 16) & 1u);   // RNE
  return (short)(x >> 16);
}
__device__ __forceinline__ float bf2f(short u) {
  union { unsigned int i; float f; } c;
  c.i = ((unsigned int)(unsigned short)u) << 16;
  return c.f;
}
__device__ __forceinline__ f32x4 mfma16(bf16x8 a, bf16x8 b, f32x4 c) {
  return __builtin_amdgcn_mfma_f32_16x16x32_bf16(a, b, c, 0, 0, 0);
}
// Async global->LDS, 16B per lane. LDS dest = wave-uniform base + lane*16.
__device__ __forceinline__ void gl_lds16(const short* g, short* l) {
  __builtin_amdgcn_global_load_lds(
      (const __attribute__((address_space(1))) unsigned int*)(const void*)g,
      (__attribute__((address_space(3))) unsigned int*)(void*)l, 16, 0, 0);
}

__global__ __launch_bounds__(256) void fill_code_f32(float* __restrict__ out,
                                                     float code)
{
  out[blockIdx.x * 256 + threadIdx.x] = code;
}

// ---------------------------------------------------------------------------
// Weight pre-transpose + f32->bf16: dst[n*K + k] = bf16(src[k*N + n]).
// ---------------------------------------------------------------------------
__global__ __launch_bounds__(256) void prep_weights(
    const float* __restrict__ Wq, const float* __restrict__ Wk,
    const float* __restrict__ Wv, const float* __restrict__ Wo,
    const float* __restrict__ W1, const float* __restrict__ W2,
    short* __restrict__ Wqkvt, short* __restrict__ Wot,
    short* __restrict__ W1t,   short* __restrict__ W2t)
{
  int gw   = blockIdx.x * 4 + (threadIdx.x >> 6);
  int lane = threadIdx.x & 63;
  int l = gw / 6144;
  int g = gw % 6144;
  const float* src; short* dst; int K, N, gi;
  if (g < 2048) {                       // Wq,Wk,Wv,Wo  (512x512 each)
    int w = g >> 9; gi = g & 511; K = 512; N = 512;
    src = (w == 0 ? Wq : w == 1 ? Wk : w == 2 ? Wv : Wo) + l * 262144;
    dst = (w < 3) ? (Wqkvt + l * 786432 + w * 262144) : (Wot + l * 262144);
  } else if (g < 4096) {                // W1 (512 x 2048)
    gi = g - 2048; K = 512; N = 2048;
    src = W1 + l * 1048576; dst = W1t + l * 1048576;
  } else {                              // W2 (2048 x 512)
    gi = g - 4096; K = 2048; N = 512;
    src = W2 + l * 1048576; dst = W2t + l * 1048576;
  }
  int nb = N >> 6;
  int n  = (gi % nb) * 64 + lane;
  int k0 = (gi / nb) * 8;
  s16x8 v;
  #pragma unroll
  for (int i = 0; i < 8; i++) v[i] = f2bf(src[(size_t)(k0 + i) * N + n]);
  *(s16x8*)(dst + (size_t)n * K + k0) = v;
}

// f32 x -> f32 residual chain copy + bf16 GEMM operand
__global__ __launch_bounds__(256) void cast_kernel(const float* __restrict__ in,
                                                   float* __restrict__ outf,
                                                   short* __restrict__ outb)
{
  int i = blockIdx.x * 256 + threadIdx.x;
  float v = in[i];
  outf[i] = v;
  outb[i] = f2bf(v);
}

// ---------------------------------------------------------------------------
// Split-K reduce: of[i] = sum_p(bf16 parts[p][i]) + bias[i&511]
//                 + (rf ? rf[i] : bf2f(rb[i])).  8 elems/thread, vectorized.
// ---------------------------------------------------------------------------
__global__ __launch_bounds__(256) void skred(
    const short* __restrict__ parts, const float* __restrict__ bias,
    const float* __restrict__ rf, const short* __restrict__ rb,
    float* __restrict__ of)
{
  const int g = blockIdx.x * 256 + threadIdx.x;   // 262144 threads
  const size_t base = (size_t)g * 8;
  float s[8];
  #pragma unroll
  for (int j = 0; j < 8; j++) s[j] = bias[(base + j) & 511];
  #pragma unroll
  for (int p = 0; p < 4; p++) {
    s16x8 v = *(const s16x8*)(parts + (size_t)p * 2097152 + base);
    #pragma unroll
    for (int j = 0; j < 8; j++) s[j] += bf2f(v[j]);
  }
  if (rf) {
    #pragma unroll
    for (int j = 0; j < 8; j++) s[j] += rf[base + j];
  } else {
    s16x8 v = *(const s16x8*)(rb + base);
    #pragma unroll
    for (int j = 0; j < 8; j++) s[j] += bf2f(v[j]);
  }
  #pragma unroll
  for (int j = 0; j < 8; j++) of[base + j] = s[j];
}

// ---------------------------------------------------------------------------
// GEMM: C(M,N) = A(M,K) @ W, W pre-transposed Bt(N,K). bf16 MFMA.
// Tile TM x 128, BK=32, 4 waves, single-buffer async gl_lds16 staging
// (harness-proven structure). Optional split-K (KS chunks, deterministic
// bf16 partials). Modes: 0=QKV scatter, 2=GELU->bf16, 4=bf16 partial write.
// ---------------------------------------------------------------------------
template<int TM>
__global__ __launch_bounds__(256) void gemm_bt(
    const short* __restrict__ A, const short* __restrict__ Bt,
    int M, int N, int K, int KS, int mode,
    const float* __restrict__ bq, const float* __restrict__ bk,
    const float* __restrict__ bv,
    short* __restrict__ oq, short* __restrict__ okk, short* __restrict__ ov)
{
  __shared__ short As[TM * 32];
  __shared__ short Bs[128 * 32];
  constexpr int MT = TM / 32;          // 16-row tiles per wave (4 or 2)
  const int tid  = threadIdx.x;
  const int lane = tid & 63;
  const int wid  = tid >> 6;
  const int lm   = lane & 15, quad = lane >> 4;
  const int nbn  = N >> 7;
  const int nb2  = (M / TM) * nbn;
  const int ks   = blockIdx.x / nb2;
  const int rem  = blockIdx.x % nb2;
  const int m0   = (rem / nbn) * TM;
  const int n0   = (rem % nbn) << 7;
  const int wm   = (wid & 1) * (TM / 2), wn = (wid >> 1) * 64;
  const int Kc   = K / KS;
  const int kbeg = ks * Kc;

  f32x4 acc[MT][4];
  #pragma unroll
  for (int i = 0; i < MT; i++)
    #pragma unroll
    for (int j = 0; j < 4; j++) acc[i][j] = (f32x4){0.f, 0.f, 0.f, 0.f};

  const short* Abase = A  + (size_t)m0 * K;
  const short* Bbase = Bt + (size_t)n0 * K;

  for (int k0 = kbeg; k0 < kbeg + Kc; k0 += 32) {
    __syncthreads();                     // prior iteration's LDS reads done
    #pragma unroll
    for (int j = 0; j < TM / 64; j++) {  // As: TM*4 chunks of 16B
      int c = j * 256 + wid * 64 + lane;
      gl_lds16(Abase + (size_t)(c >> 2) * K + k0 + (c & 3) * 8,
               &As[(j * 256 + wid * 64) * 8]);
    }
    #pragma unroll
    for (int j = 0; j < 2; j++) {        // Bs: 512 chunks
      int c = j * 256 + wid * 64 + lane;
      gl_lds16(Bbase + (size_t)(c >> 2) * K + k0 + (c & 3) * 8,
               &Bs[(j * 256 + wid * 64) * 8]);
    }
    __syncthreads();                     // drains vmcnt -> tiles in LDS
    bf16x8 af[MT], bfr[4];
    #pragma unroll
    for (int t = 0; t < MT; t++)
      af[t] = *(const bf16x8*)&As[(wm + t * 16 + lm) * 32 + quad * 8];
    #pragma unroll
    for (int t = 0; t < 4; t++)
      bfr[t] = *(const bf16x8*)&Bs[(wn + t * 16 + lm) * 32 + quad * 8];
    #pragma unroll
    for (int mt = 0; mt < MT; mt++)
      #pragma unroll
      for (int nt = 0; nt < 4; nt++)
        acc[mt][nt] = mfma16(af[mt], bfr[nt], acc[mt][nt]);
  }

  #pragma unroll
  for (int mt = 0; mt < MT; mt++) {
    int row = m0 + wm + mt * 16 + quad * 4;
    #pragma unroll
    for (int nt = 0; nt < 4; nt++) {
      int col = n0 + wn + nt * 16 + lm;
      f32x4 v = acc[mt][nt];
      if (mode == 0) {                       // QKV scatter, N=1536
        int which = col >> 9; int d = col & 511;
        int hh = d >> 6; int e = d & 63;
        const float* bias = which == 0 ? bq : which == 1 ? bk : bv;
        float bb = bias[d];
        #pragma unroll
        for (int r = 0; r < 4; r++) {
          int tok = row + r; int bI = tok >> 11, li = tok & 2047;
          float val = v[r] + bb;
          if (which == 0)
            oq [(((size_t)bI * NH + hh) * SEQ + li) * EH + e] = f2bf(val);
          else if (which == 1)
            okk[(((size_t)bI * NH + hh) * SEQ + li) * EH + e] = f2bf(val);
          else
            ov [(((size_t)bI * NH + hh) * EH + e) * SEQ + li] = f2bf(val);
        }
      } else if (mode == 2) {                // GELU -> bf16
        float bb = bq[col];
        #pragma unroll
        for (int r = 0; r < 4; r++) {
          float x = v[r] + bb;
          float u = 0.7978845608f * (x + 0.044715f * x * x * x);
          float t = 1.f - 2.f / (1.f + __expf(2.f * u));   // tanh, safe
          size_t idx = (size_t)(row + r) * N + col;
          oq[idx] = f2bf(0.5f * x * (1.f + t));
        }
      } else {                               // mode 4: bf16 split-K partial
        short* op = oq + (size_t)ks * M * N;
        #pragma unroll
        for (int r = 0; r < 4; r++)
          op[(size_t)(row + r) * N + col] = f2bf(v[r]);
      }
    }
  }
}

// ---------------------------------------------------------------------------
// Flash attention v7 (harness-proven): fixed-bias softmax + 4-way key split.
// ---------------------------------------------------------------------------
__global__ __launch_bounds__(256) void attn_v7(
    const short* __restrict__ Q, const short* __restrict__ Kg,
    const short* __restrict__ Vt,
    const float* __restrict__ tau, const float* __restrict__ delta,
    short* __restrict__ opart, float* __restrict__ lpart)
{
  __shared__ short Ks[64 * 72];       // [key][e]
  __shared__ short Vs[64 * 72];       // [e][key]
  __shared__ short Ps[4][16 * 72];    // per-wave P scratch [q][key]
  const int tid  = threadIdx.x;
  const int lane = tid & 63, wid = tid >> 6;
  const int lm = lane & 15, quad = lane >> 4;
  const int t    = blockIdx.x >> 2;   // tile id
  const int part = blockIdx.x & 3;    // key quarter
  const int qb = 31 - (t & 31);       // reversed: big-work blocks first
  const int h  = (t >> 5) & 7;
  const int b  = t >> 8;
  const int q0 = qb * 64;
  const int qw = q0 + wid * 16;
  const size_t bhq = ((size_t)b * NH + h) * SEQ;
  const short* kbase = Kg + bhq * EH;
  const short* vbase = Vt + ((size_t)b * NH + h) * (size_t)(EH * SEQ);

  const int nblk = qb + 1;
  const int kb0 = (nblk * part) >> 2;
  const int kb1 = (nblk * (part + 1)) >> 2;

  bf16x8 qf0 = *(const bf16x8*)(Q + (bhq + qw + lm) * EH + quad * 8);
  bf16x8 qf1 = *(const bf16x8*)(Q + (bhq + qw + lm) * EH + 32 + quad * 8);

  const float st2 = 0.125f * LOG2E * tau[b];
  f32x4 O[4];
  #pragma unroll
  for (int i = 0; i < 4; i++) O[i] = (f32x4){0.f, 0.f, 0.f, 0.f};
  float lr[4] = {0.f, 0.f, 0.f, 0.f};   // per-lane partial row sums

  const int c0 = tid, c1 = tid + 256;      // 512 chunks of 8 shorts per tile
  const int r0 = c0 >> 3, ch0 = (c0 & 7) * 8;
  const int r1 = c1 >> 3, ch1 = (c1 & 7) * 8;

  for (int kb = kb0; kb < kb1; kb++) {
    const int s0 = kb << 6;
    s16x8 ka = *(const s16x8*)(kbase + (size_t)(s0 + r0) * EH + ch0);
    s16x8 kb_ = *(const s16x8*)(kbase + (size_t)(s0 + r1) * EH + ch1);
    s16x8 va = *(const s16x8*)(vbase + (size_t)r0 * SEQ + s0 + ch0);
    s16x8 vb = *(const s16x8*)(vbase + (size_t)r1 * SEQ + s0 + ch1);
    __syncthreads();                  // prior iteration's LDS reads done
    *(s16x8*)&Ks[r0 * 72 + ch0] = ka;
    *(s16x8*)&Ks[r1 * 72 + ch1] = kb_;
    *(s16x8*)&Vs[r0 * 72 + ch0] = va;
    *(s16x8*)&Vs[r1 * 72 + ch1] = vb;
    __syncthreads();

    // QK^T: 16 q x 64 keys
    f32x4 S[4];
    #pragma unroll
    for (int nt = 0; nt < 4; nt++) {
      S[nt] = (f32x4){0.f, 0.f, 0.f, 0.f};
      S[nt] = mfma16(qf0, *(const bf16x8*)&Ks[(nt*16 + lm) * 72 + quad * 8], S[nt]);
      S[nt] = mfma16(qf1, *(const bf16x8*)&Ks[(nt*16 + lm) * 72 + 32 + quad * 8], S[nt]);
    }
    float dl[4];
    #pragma unroll
    for (int nt = 0; nt < 4; nt++)    // delta in log2 domain, minus fixed M=8
      dl[nt] = fmaf(0.125f * LOG2E, delta[(size_t)b * SEQ + s0 + nt * 16 + lm],
                    -8.f);

    const bool diag = (kb == qb);
    #pragma unroll
    for (int r = 0; r < 4; r++) {
      float sc[4];
      #pragma unroll
      for (int nt = 0; nt < 4; nt++) sc[nt] = fmaf(st2, S[nt][r], dl[nt]);
      if (diag) {
        int rowq = qw + quad * 4 + r;
        #pragma unroll
        for (int nt = 0; nt < 4; nt++)
          if (s0 + nt * 16 + lm > rowq) sc[nt] = -__builtin_inff();
      }
      float p0 = exp2f(sc[0]), p1 = exp2f(sc[1]);
      float p2 = exp2f(sc[2]), p3 = exp2f(sc[3]);
      lr[r] += (p0 + p1) + (p2 + p3);
      short* pr = &Ps[wid][(quad * 4 + r) * 72];
      pr[lm]      = f2bf(p0);
      pr[16 + lm] = f2bf(p1);
      pr[32 + lm] = f2bf(p2);
      pr[48 + lm] = f2bf(p3);
    }

    // PV: P (16x64, per-wave LDS) @ V (64 keys x 64 e)
    bf16x8 pf0 = *(const bf16x8*)&Ps[wid][lm * 72 + quad * 8];
    bf16x8 pf1 = *(const bf16x8*)&Ps[wid][lm * 72 + 32 + quad * 8];
    #pragma unroll
    for (int et = 0; et < 4; et++) {
      O[et] = mfma16(pf0, *(const bf16x8*)&Vs[(et*16 + lm) * 72 + quad * 8], O[et]);
      O[et] = mfma16(pf1, *(const bf16x8*)&Vs[(et*16 + lm) * 72 + 32 + quad * 8], O[et]);
    }
  }

  // Reduce lr across the 16 lanes of each row group (once).
  #pragma unroll
  for (int r = 0; r < 4; r++) {
    float s = lr[r];
    #pragma unroll
    for (int off = 1; off < 16; off <<= 1) s += __shfl_xor(s, off);
    lr[r] = s;
  }

  // Write partials: O (bf16) to opart[slot], l (f32) to lpart[slot].
  const int slot = ((t << 2) | part);
  short* ob = opart + (size_t)slot * 4096;
  float* lb = lpart + (size_t)slot * 64;
  #pragma unroll
  for (int r = 0; r < 4; r++) {
    int qloc = wid * 16 + quad * 4 + r;
    #pragma unroll
    for (int et = 0; et < 4; et++)
      ob[qloc * 64 + et * 16 + lm] = f2bf(O[et][r]);
    if (lm == 0) lb[qloc] = lr[r];
  }
}

// Combine the 4 key-quarter partials, normalize, write bf16 at16 (B*L, D).
__global__ __launch_bounds__(256) void attn_reduce(
    const short* __restrict__ opart, const float* __restrict__ lpart,
    short* __restrict__ Oa)
{
  const int t = blockIdx.x;           // tile id (matches attn_v7 mapping)
  const int qb = 31 - (t & 31);
  const int h  = (t >> 5) & 7;
  const int b  = t >> 8;
  const int q0 = qb * 64;
  #pragma unroll
  for (int i = 0; i < 16; i++) {
    int idx = i * 256 + threadIdx.x;
    int q = idx >> 6, e = idx & 63;
    float l = 0.f, o = 0.f;
    #pragma unroll
    for (int p = 0; p < 4; p++) {
      int slot = t * 4 + p;
      l += lpart[(size_t)slot * 64 + q];
      o += bf2f(opart[(size_t)slot * 4096 + idx]);
    }
    Oa[((size_t)b * SEQ + q0 + q) * DM + h * EH + e] = f2bf(o / l);
  }
}

// ---------------------------------------------------------------------------
// LayerNorm over D=512. One wave per row. f32 in; optional f32 out (may be
// in-place) + optional bf16 out.
// ---------------------------------------------------------------------------
__global__ __launch_bounds__(256) void ln_kernel(
    const float* in, const float* __restrict__ g, const float* __restrict__ bb,
    float* outf, short* outb)
{
  int row  = blockIdx.x * 4 + (threadIdx.x >> 6);
  int lane = threadIdx.x & 63;
  const float* p = in + (size_t)row * DM;
  float v[8]; float s = 0.f, ss = 0.f;
  #pragma unroll
  for (int i = 0; i < 8; i++) {
    float x = p[lane + i * 64]; v[i] = x; s += x; ss += x * x;
  }
  #pragma unroll
  for (int off = 32; off > 0; off >>= 1) {
    s += __shfl_xor(s, off); ss += __shfl_xor(ss, off);
  }
  float mean = s * (1.f / DM);
  float var  = ss * (1.f / DM) - mean * mean;
  float rstd = rsqrtf(var + 1e-5f);
  #pragma unroll
  for (int i = 0; i < 8; i++) {
    int c = lane + i * 64;
    float y = (v[i] - mean) * rstd * g[c] + bb[c];
    if (outf) outf[(size_t)row * DM + c] = y;
    if (outb) outb[(size_t)row * DM + c] = f2bf(y);
  }
}

// ---------------------------------------------------------------------------
extern "C" void kernel_launch(void* const* d_in, const int* in_sizes, int n_in,
                              void* d_out, int out_size, void* d_ws, size_t ws_size,
                              hipStream_t stream)
{
  float* out = (float*)d_out;          // f32 output

  if (ws_size < (size_t)62918656) {    // 60 MB + safety
    fill_code_f32<<<2097152 / 256, 256, 0, stream>>>(
        out, 1200.f + (float)(ws_size >> 20));
    return;
  }

  const float* x    = (const float*)d_in[0];
  const float* tau  = (const float*)d_in[1];
  const float* del  = (const float*)d_in[2];
  const float* Wq = (const float*)d_in[4];
  const float* bq = (const float*)d_in[5];
  const float* Wk = (const float*)d_in[6];
  const float* bk = (const float*)d_in[7];
  const float* Wv = (const float*)d_in[8];
  const float* bv = (const float*)d_in[9];
  const float* Wo = (const float*)d_in[10];
  const float* bo = (const float*)d_in[11];
  const float* W1 = (const float*)d_in[12];
  const float* b1 = (const float*)d_in[13];
  const float* W2 = (const float*)d_in[14];
  const float* b2 = (const float*)d_in[15];
  const float* ln1g = (const float*)d_in[16];
  const float* ln1b = (const float*)d_in[17];
  const float* ln2g = (const float*)d_in[18];
  const float* ln2b = (const float*)d_in[19];
  const float* lnfg = (const float*)d_in[20];
  const float* lnfb = (const float*)d_in[21];

  char* ws = (char*)d_ws;
  float* sumf  = (float*)(ws + 0);          //  8 MB  fp32 residual chain (x)
  short* x16   = (short*)(ws + 8388608);    //  4 MB  bf16 x (GEMM A operand)
  short* xb16  = (short*)(ws + 12582912);   //  4 MB  LN1 out (xb)
  short* q16   = (short*)(ws + 16777216);   //  4 MB  (B,H,L,E)
  short* k16   = (short*)(ws + 20971520);   //  4 MB  (B,H,L,E)
  short* vt16  = (short*)(ws + 25165824);   //  4 MB  (B,H,E,L)
  short* at16  = (short*)(ws + 29360128);   //  4 MB  attention out (B*L, D)
  short* h16   = (short*)(ws + 33554432);   // 16 MB  FFN hidden
  short* Wqkvt = (short*)(ws + 50331648);   //  3 MB
  short* Wot   = (short*)(ws + 53477376);   //  1 MB
  short* W1t   = (short*)(ws + 54525952);   //  4 MB
  short* W2t   = (short*)(ws + 58720256);   //  4 MB  (total 60 MB)
  // Overlays (regions dead at time of use):
  short* aopart = (short*)(ws + 33554432);  // attn O partials (h16, 16 MB)
  float* alpart = (float*)(ws + 12582912);  // attn l partials (xb16, 512 KB)
  short* oppart = (short*)(ws + 33554432);  // O-proj split-K partials (h16)
  short* f2part = (short*)(ws + 16777216);  // FFN2 split-K partials
                                            //   (q16..at16, 16 MB)

  prep_weights<<<3072, 256, 0, stream>>>(Wq, Wk, Wv, Wo, W1, W2,
                                         Wqkvt, Wot, W1t, W2t);
  cast_kernel<<<NTOK * DM / 256, 256, 0, stream>>>(x, sumf, x16);

  for (int l = 0; l < 2; l++) {
    // QKV (N=1536, K=512) -- TM=64: 768 blocks (3/CU)
    gemm_bt<64><<<64 * 12, 256, 0, stream>>>(x16, Wqkvt + l * 786432,
        NTOK, 3 * DM, DM, 1, 0,
        bq + l * DM, bk + l * DM, bv + l * DM,
        q16, k16, vt16);
    attn_v7<<<4 * NBAT * NH * (SEQ / 64), 256, 0, stream>>>(
        q16, k16, vt16, tau, del, aopart, alpart);
    attn_reduce<<<NBAT * NH * (SEQ / 64), 256, 0, stream>>>(
        aopart, alpart, at16);
    // O-proj: split-K x4, bf16 partials -> skred adds bias + f32 resid (sumf)
    gemm_bt<64><<<64 * 4 * 4, 256, 0, stream>>>(at16, Wot + l * 262144,
        NTOK, DM, DM, 4, 4,
        nullptr, nullptr, nullptr,
        oppart, nullptr, nullptr);
    skred<<<1024, 256, 0, stream>>>(oppart, bo + l * DM, sumf, nullptr, sumf);
    ln_kernel<<<NTOK / 4, 256, 0, stream>>>(sumf, ln1g + l * DM, ln1b + l * DM,
                                            nullptr, xb16);
    // FFN1 + GELU (N=2048, K=512) -- TM=64: 1024 blocks (4/CU)
    gemm_bt<64><<<64 * 16, 256, 0, stream>>>(xb16, W1t + l * 1048576,
        NTOK, DFF, DM, 1, 2,
        b1 + l * DFF, nullptr, nullptr,
        h16, nullptr, nullptr);
    // FFN2: split-K x4, bf16 partials -> skred adds bias + bf16 resid (xb16)
    gemm_bt<64><<<64 * 4 * 4, 256, 0, stream>>>(h16, W2t + l * 1048576,
        NTOK, DM, DFF, 4, 4,
        nullptr, nullptr, nullptr,
        f2part, nullptr, nullptr);
    skred<<<1024, 256, 0, stream>>>(f2part, b2 + l * DM, nullptr, xb16, sumf);
    // LN2 -> sumf (in place) + x16 (bf16 x for next layer's QKV)
    ln_kernel<<<NTOK / 4, 256, 0, stream>>>(sumf, ln2g + l * DM, ln2b + l * DM,
                                            sumf, x16);
  }
  ln_kernel<<<NTOK / 4, 256, 0, stream>>>(sumf, lnfg, lnfb, out, nullptr);
}

// Round 16
// 405.827 us; speedup vs baseline: 1.2524x; 1.0775x over previous
//
#include <hip/hip_runtime.h>
#include <stdint.h>

// Problem constants (fixed-size problem)
#define DM   512
#define DFF  2048
#define NH   8
#define EH   64
#define SEQ  2048
#define NBAT 2
#define NTOK (NBAT*SEQ)   // 4096
#define LOG2E 1.44269504088896340736f

typedef __attribute__((ext_vector_type(8))) short  s16x8;
typedef __attribute__((ext_vector_type(8))) __bf16 bf16x8;
typedef __attribute__((ext_vector_type(4))) float  f32x4;

__device__ __forceinline__ short f2bf(float f) {
  union { float f; unsigned int i; } c; c.f = f;
  unsigned int x = c.i;
  x += 0x7fffu + ((x >> 16) & 1u);   // RNE
  return (short)(x >> 16);
}
__device__ __forceinline__ float bf2f(short u) {
  union { unsigned int i; float f; } c;
  c.i = ((unsigned int)(unsigned short)u) << 16;
  return c.f;
}
__device__ __forceinline__ f32x4 mfma16(bf16x8 a, bf16x8 b, f32x4 c) {
  return __builtin_amdgcn_mfma_f32_16x16x32_bf16(a, b, c, 0, 0, 0);
}
// Async global->LDS, 16B per lane. LDS dest = wave-uniform base + lane*16.
__device__ __forceinline__ void gl_lds16(const short* g, short* l) {
  __builtin_amdgcn_global_load_lds(
      (const __attribute__((address_space(1))) unsigned int*)(const void*)g,
      (__attribute__((address_space(3))) unsigned int*)(void*)l, 16, 0, 0);
}

__global__ __launch_bounds__(256) void fill_code_f32(float* __restrict__ out,
                                                     float code)
{
  out[blockIdx.x * 256 + threadIdx.x] = code;
}

// ---------------------------------------------------------------------------
// Weight pre-transpose + f32->bf16: dst[n*K + k] = bf16(src[k*N + n]).
// ---------------------------------------------------------------------------
__global__ __launch_bounds__(256) void prep_weights(
    const float* __restrict__ Wq, const float* __restrict__ Wk,
    const float* __restrict__ Wv, const float* __restrict__ Wo,
    const float* __restrict__ W1, const float* __restrict__ W2,
    short* __restrict__ Wqkvt, short* __restrict__ Wot,
    short* __restrict__ W1t,   short* __restrict__ W2t)
{
  int gw   = blockIdx.x * 4 + (threadIdx.x >> 6);
  int lane = threadIdx.x & 63;
  int l = gw / 6144;
  int g = gw % 6144;
  const float* src; short* dst; int K, N, gi;
  if (g < 2048) {                       // Wq,Wk,Wv,Wo  (512x512 each)
    int w = g >> 9; gi = g & 511; K = 512; N = 512;
    src = (w == 0 ? Wq : w == 1 ? Wk : w == 2 ? Wv : Wo) + l * 262144;
    dst = (w < 3) ? (Wqkvt + l * 786432 + w * 262144) : (Wot + l * 262144);
  } else if (g < 4096) {                // W1 (512 x 2048)
    gi = g - 2048; K = 512; N = 2048;
    src = W1 + l * 1048576; dst = W1t + l * 1048576;
  } else {                              // W2 (2048 x 512)
    gi = g - 4096; K = 2048; N = 512;
    src = W2 + l * 1048576; dst = W2t + l * 1048576;
  }
  int nb = N >> 6;
  int n  = (gi % nb) * 64 + lane;
  int k0 = (gi / nb) * 8;
  s16x8 v;
  #pragma unroll
  for (int i = 0; i < 8; i++) v[i] = f2bf(src[(size_t)(k0 + i) * N + n]);
  *(s16x8*)(dst + (size_t)n * K + k0) = v;
}

// f32 x -> f32 residual chain copy + bf16 GEMM operand
__global__ __launch_bounds__(256) void cast_kernel(const float* __restrict__ in,
                                                   float* __restrict__ outf,
                                                   short* __restrict__ outb)
{
  int i = blockIdx.x * 256 + threadIdx.x;
  float v = in[i];
  outf[i] = v;
  outb[i] = f2bf(v);
}

// ---------------------------------------------------------------------------
// Fused split-K reduce + LayerNorm. One wave per row (D=512, 8 elems/lane).
// t = sum_p(bf16 parts[p]) + bias + resid (rf f32 | rb bf16)
// mode 0 (O-proj): sumf = t          ; outb = bf16(LN(t))   (xb for FFN)
// mode 1 (FFN2)  : sumf = LN(t) (f32); outb = bf16(LN(t))   (next-layer x)
// ---------------------------------------------------------------------------
__global__ __launch_bounds__(256) void skred_ln(
    const short* __restrict__ parts, const float* __restrict__ bias,
    const float* __restrict__ rf, const short* __restrict__ rb,
    const float* __restrict__ g, const float* __restrict__ bb,
    float* __restrict__ sumf, short* __restrict__ outb, int mode)
{
  const int row  = blockIdx.x * 4 + (threadIdx.x >> 6);
  const int lane = threadIdx.x & 63;
  const int col  = lane * 8;
  const size_t base = (size_t)row * DM + col;
  float t[8];
  #pragma unroll
  for (int j = 0; j < 8; j++) t[j] = bias[col + j];
  #pragma unroll
  for (int p = 0; p < 4; p++) {
    s16x8 v = *(const s16x8*)(parts + (size_t)p * (NTOK * DM) + base);
    #pragma unroll
    for (int j = 0; j < 8; j++) t[j] += bf2f(v[j]);
  }
  if (mode == 0) {
    #pragma unroll
    for (int j = 0; j < 8; j++) t[j] += rf[base + j];
  } else {
    s16x8 v = *(const s16x8*)(rb + base);
    #pragma unroll
    for (int j = 0; j < 8; j++) t[j] += bf2f(v[j]);
  }
  float s = 0.f, ss = 0.f;
  #pragma unroll
  for (int j = 0; j < 8; j++) { s += t[j]; ss += t[j] * t[j]; }
  #pragma unroll
  for (int off = 32; off > 0; off >>= 1) {
    s += __shfl_xor(s, off); ss += __shfl_xor(ss, off);
  }
  float mean = s * (1.f / DM);
  float var  = ss * (1.f / DM) - mean * mean;
  float rstd = rsqrtf(var + 1e-5f);
  if (mode == 0) {
    #pragma unroll
    for (int j = 0; j < 8; j++) {
      sumf[base + j] = t[j];
      outb[base + j] = f2bf((t[j] - mean) * rstd * g[col + j] + bb[col + j]);
    }
  } else {
    #pragma unroll
    for (int j = 0; j < 8; j++) {
      float y = (t[j] - mean) * rstd * g[col + j] + bb[col + j];
      sumf[base + j] = y;
      outb[base + j] = f2bf(y);
    }
  }
}

// ---------------------------------------------------------------------------
// GEMM: C(M,N) = A(M,K) @ W, W pre-transposed Bt(N,K). bf16 MFMA.
// Tile TM x 128, BK=64 staged as two stride-32 halves per barrier pair
// (round-12 harness-proven staging). Optional split-K (KS chunks,
// deterministic bf16 partials). Modes: 0=QKV scatter, 2=GELU->bf16,
// 4=bf16 partial write.
// ---------------------------------------------------------------------------
template<int TM>
__global__ __launch_bounds__(256) void gemm_bt(
    const short* __restrict__ A, const short* __restrict__ Bt,
    int M, int N, int K, int KS, int mode,
    const float* __restrict__ bq, const float* __restrict__ bk,
    const float* __restrict__ bv,
    short* __restrict__ oq, short* __restrict__ okk, short* __restrict__ ov)
{
  __shared__ short As[2][TM * 32];     // two K-halves, proven layout each
  __shared__ short Bs[2][128 * 32];
  constexpr int MT = TM / 32;          // 16-row tiles per wave (4 or 2)
  const int tid  = threadIdx.x;
  const int lane = tid & 63;
  const int wid  = tid >> 6;
  const int lm   = lane & 15, quad = lane >> 4;
  const int nbn  = N >> 7;
  const int nb2  = (M / TM) * nbn;
  const int ks   = blockIdx.x / nb2;
  const int rem  = blockIdx.x % nb2;
  const int m0   = (rem / nbn) * TM;
  const int n0   = (rem % nbn) << 7;
  const int wm   = (wid & 1) * (TM / 2), wn = (wid >> 1) * 64;
  const int Kc   = K / KS;
  const int kbeg = ks * Kc;

  f32x4 acc[MT][4];
  #pragma unroll
  for (int i = 0; i < MT; i++)
    #pragma unroll
    for (int j = 0; j < 4; j++) acc[i][j] = (f32x4){0.f, 0.f, 0.f, 0.f};

  const short* Abase = A  + (size_t)m0 * K;
  const short* Bbase = Bt + (size_t)n0 * K;

  for (int k0 = kbeg; k0 < kbeg + Kc; k0 += 64) {
    __syncthreads();                     // prior iteration's LDS reads done
    #pragma unroll
    for (int half = 0; half < 2; half++) {
      const int kk = k0 + half * 32;
      #pragma unroll
      for (int j = 0; j < TM / 64; j++) {  // As half: TM*4 chunks of 16B
        int c = j * 256 + wid * 64 + lane;
        gl_lds16(Abase + (size_t)(c >> 2) * K + kk + (c & 3) * 8,
                 &As[half][(j * 256 + wid * 64) * 8]);
      }
      #pragma unroll
      for (int j = 0; j < 2; j++) {        // Bs half: 512 chunks
        int c = j * 256 + wid * 64 + lane;
        gl_lds16(Bbase + (size_t)(c >> 2) * K + kk + (c & 3) * 8,
                 &Bs[half][(j * 256 + wid * 64) * 8]);
      }
    }
    __syncthreads();                     // drains vmcnt -> tiles in LDS
    #pragma unroll
    for (int half = 0; half < 2; half++) {
      bf16x8 af[MT], bfr[4];
      #pragma unroll
      for (int t = 0; t < MT; t++)
        af[t] = *(const bf16x8*)&As[half][(wm + t * 16 + lm) * 32 + quad * 8];
      #pragma unroll
      for (int t = 0; t < 4; t++)
        bfr[t] = *(const bf16x8*)&Bs[half][(wn + t * 16 + lm) * 32 + quad * 8];
      #pragma unroll
      for (int mt = 0; mt < MT; mt++)
        #pragma unroll
        for (int nt = 0; nt < 4; nt++)
          acc[mt][nt] = mfma16(af[mt], bfr[nt], acc[mt][nt]);
    }
  }

  #pragma unroll
  for (int mt = 0; mt < MT; mt++) {
    int row = m0 + wm + mt * 16 + quad * 4;
    #pragma unroll
    for (int nt = 0; nt < 4; nt++) {
      int col = n0 + wn + nt * 16 + lm;
      f32x4 v = acc[mt][nt];
      if (mode == 0) {                       // QKV scatter, N=1536
        int which = col >> 9; int d = col & 511;
        int hh = d >> 6; int e = d & 63;
        const float* bias = which == 0 ? bq : which == 1 ? bk : bv;
        float bb = bias[d];
        #pragma unroll
        for (int r = 0; r < 4; r++) {
          int tok = row + r; int bI = tok >> 11, li = tok & 2047;
          float val = v[r] + bb;
          if (which == 0)
            oq [(((size_t)bI * NH + hh) * SEQ + li) * EH + e] = f2bf(val);
          else if (which == 1)
            okk[(((size_t)bI * NH + hh) * SEQ + li) * EH + e] = f2bf(val);
          else
            ov [(((size_t)bI * NH + hh) * EH + e) * SEQ + li] = f2bf(val);
        }
      } else if (mode == 2) {                // GELU -> bf16
        float bb = bq[col];
        #pragma unroll
        for (int r = 0; r < 4; r++) {
          float x = v[r] + bb;
          float u = 0.7978845608f * (x + 0.044715f * x * x * x);
          float t = 1.f - 2.f / (1.f + __expf(2.f * u));   // tanh, safe
          size_t idx = (size_t)(row + r) * N + col;
          oq[idx] = f2bf(0.5f * x * (1.f + t));
        }
      } else {                               // mode 4: bf16 split-K partial
        short* op = oq + (size_t)ks * M * N;
        #pragma unroll
        for (int r = 0; r < 4; r++)
          op[(size_t)(row + r) * N + col] = f2bf(v[r]);
      }
    }
  }
}

// ---------------------------------------------------------------------------
// Flash attention v7b: fixed-bias softmax + 4-way key split (proven), with
// P stored via TRUNCATION (1 op vs 4-op RNE) and l accumulated from the
// truncated values so the o/l bias cancels.
// ---------------------------------------------------------------------------
__global__ __launch_bounds__(256) void attn_v7(
    const short* __restrict__ Q, const short* __restrict__ Kg,
    const short* __restrict__ Vt,
    const float* __restrict__ tau, const float* __restrict__ delta,
    short* __restrict__ opart, float* __restrict__ lpart)
{
  __shared__ short Ks[64 * 72];       // [key][e]
  __shared__ short Vs[64 * 72];       // [e][key]
  __shared__ short Ps[4][16 * 72];    // per-wave P scratch [q][key]
  const int tid  = threadIdx.x;
  const int lane = tid & 63, wid = tid >> 6;
  const int lm = lane & 15, quad = lane >> 4;
  const int t    = blockIdx.x >> 2;   // tile id
  const int part = blockIdx.x & 3;    // key quarter
  const int qb = 31 - (t & 31);       // reversed: big-work blocks first
  const int h  = (t >> 5) & 7;
  const int b  = t >> 8;
  const int q0 = qb * 64;
  const int qw = q0 + wid * 16;
  const size_t bhq = ((size_t)b * NH + h) * SEQ;
  const short* kbase = Kg + bhq * EH;
  const short* vbase = Vt + ((size_t)b * NH + h) * (size_t)(EH * SEQ);

  const int nblk = qb + 1;
  const int kb0 = (nblk * part) >> 2;
  const int kb1 = (nblk * (part + 1)) >> 2;

  bf16x8 qf0 = *(const bf16x8*)(Q + (bhq + qw + lm) * EH + quad * 8);
  bf16x8 qf1 = *(const bf16x8*)(Q + (bhq + qw + lm) * EH + 32 + quad * 8);

  const float st2 = 0.125f * LOG2E * tau[b];
  f32x4 O[4];
  #pragma unroll
  for (int i = 0; i < 4; i++) O[i] = (f32x4){0.f, 0.f, 0.f, 0.f};
  float lr[4] = {0.f, 0.f, 0.f, 0.f};   // per-lane partial row sums

  const int c0 = tid, c1 = tid + 256;      // 512 chunks of 8 shorts per tile
  const int r0 = c0 >> 3, ch0 = (c0 & 7) * 8;
  const int r1 = c1 >> 3, ch1 = (c1 & 7) * 8;

  for (int kb = kb0; kb < kb1; kb++) {
    const int s0 = kb << 6;
    s16x8 ka = *(const s16x8*)(kbase + (size_t)(s0 + r0) * EH + ch0);
    s16x8 kb_ = *(const s16x8*)(kbase + (size_t)(s0 + r1) * EH + ch1);
    s16x8 va = *(const s16x8*)(vbase + (size_t)r0 * SEQ + s0 + ch0);
    s16x8 vb = *(const s16x8*)(vbase + (size_t)r1 * SEQ + s0 + ch1);
    __syncthreads();                  // prior iteration's LDS reads done
    *(s16x8*)&Ks[r0 * 72 + ch0] = ka;
    *(s16x8*)&Ks[r1 * 72 + ch1] = kb_;
    *(s16x8*)&Vs[r0 * 72 + ch0] = va;
    *(s16x8*)&Vs[r1 * 72 + ch1] = vb;
    __syncthreads();

    // QK^T: 16 q x 64 keys
    f32x4 S[4];
    #pragma unroll
    for (int nt = 0; nt < 4; nt++) {
      S[nt] = (f32x4){0.f, 0.f, 0.f, 0.f};
      S[nt] = mfma16(qf0, *(const bf16x8*)&Ks[(nt*16 + lm) * 72 + quad * 8], S[nt]);
      S[nt] = mfma16(qf1, *(const bf16x8*)&Ks[(nt*16 + lm) * 72 + 32 + quad * 8], S[nt]);
    }
    float dl[4];
    #pragma unroll
    for (int nt = 0; nt < 4; nt++)    // delta in log2 domain, minus fixed M=8
      dl[nt] = fmaf(0.125f * LOG2E, delta[(size_t)b * SEQ + s0 + nt * 16 + lm],
                    -8.f);

    const bool diag = (kb == qb);
    #pragma unroll
    for (int r = 0; r < 4; r++) {
      float sc[4];
      #pragma unroll
      for (int nt = 0; nt < 4; nt++) sc[nt] = fmaf(st2, S[nt][r], dl[nt]);
      if (diag) {
        int rowq = qw + quad * 4 + r;
        #pragma unroll
        for (int nt = 0; nt < 4; nt++)
          if (s0 + nt * 16 + lm > rowq) sc[nt] = -__builtin_inff();
      }
      unsigned int u0 = __float_as_uint(exp2f(sc[0]));
      unsigned int u1 = __float_as_uint(exp2f(sc[1]));
      unsigned int u2 = __float_as_uint(exp2f(sc[2]));
      unsigned int u3 = __float_as_uint(exp2f(sc[3]));
      // l sums the TRUNCATED values (consistent with P) -> bias cancels
      lr[r] += (__uint_as_float(u0 & 0xffff0000u) +
                __uint_as_float(u1 & 0xffff0000u)) +
               (__uint_as_float(u2 & 0xffff0000u) +
                __uint_as_float(u3 & 0xffff0000u));
      short* pr = &Ps[wid][(quad * 4 + r) * 72];
      pr[lm]      = (short)(u0 >> 16);
      pr[16 + lm] = (short)(u1 >> 16);
      pr[32 + lm] = (short)(u2 >> 16);
      pr[48 + lm] = (short)(u3 >> 16);
    }

    // PV: P (16x64, per-wave LDS) @ V (64 keys x 64 e)
    bf16x8 pf0 = *(const bf16x8*)&Ps[wid][lm * 72 + quad * 8];
    bf16x8 pf1 = *(const bf16x8*)&Ps[wid][lm * 72 + 32 + quad * 8];
    #pragma unroll
    for (int et = 0; et < 4; et++) {
      O[et] = mfma16(pf0, *(const bf16x8*)&Vs[(et*16 + lm) * 72 + quad * 8], O[et]);
      O[et] = mfma16(pf1, *(const bf16x8*)&Vs[(et*16 + lm) * 72 + 32 + quad * 8], O[et]);
    }
  }

  // Reduce lr across the 16 lanes of each row group (once).
  #pragma unroll
  for (int r = 0; r < 4; r++) {
    float s = lr[r];
    #pragma unroll
    for (int off = 1; off < 16; off <<= 1) s += __shfl_xor(s, off);
    lr[r] = s;
  }

  // Write partials: O (bf16) to opart[slot], l (f32) to lpart[slot].
  const int slot = ((t << 2) | part);
  short* ob = opart + (size_t)slot * 4096;
  float* lb = lpart + (size_t)slot * 64;
  #pragma unroll
  for (int r = 0; r < 4; r++) {
    int qloc = wid * 16 + quad * 4 + r;
    #pragma unroll
    for (int et = 0; et < 4; et++)
      ob[qloc * 64 + et * 16 + lm] = f2bf(O[et][r]);
    if (lm == 0) lb[qloc] = lr[r];
  }
}

// Combine the 4 key-quarter partials, normalize, write bf16 at16 (B*L, D).
__global__ __launch_bounds__(256) void attn_reduce(
    const short* __restrict__ opart, const float* __restrict__ lpart,
    short* __restrict__ Oa)
{
  const int t = blockIdx.x;           // tile id (matches attn_v7 mapping)
  const int qb = 31 - (t & 31);
  const int h  = (t >> 5) & 7;
  const int b  = t >> 8;
  const int q0 = qb * 64;
  #pragma unroll
  for (int i = 0; i < 16; i++) {
    int idx = i * 256 + threadIdx.x;
    int q = idx >> 6, e = idx & 63;
    float l = 0.f, o = 0.f;
    #pragma unroll
    for (int p = 0; p < 4; p++) {
      int slot = t * 4 + p;
      l += lpart[(size_t)slot * 64 + q];
      o += bf2f(opart[(size_t)slot * 4096 + idx]);
    }
    Oa[((size_t)b * SEQ + q0 + q) * DM + h * EH + e] = f2bf(o / l);
  }
}

// ---------------------------------------------------------------------------
// LayerNorm over D=512. One wave per row. f32 in; optional f32 out (may be
// in-place) + optional bf16 out.  (Used only for the final LN.)
// ---------------------------------------------------------------------------
__global__ __launch_bounds__(256) void ln_kernel(
    const float* in, const float* __restrict__ g, const float* __restrict__ bb,
    float* outf, short* outb)
{
  int row  = blockIdx.x * 4 + (threadIdx.x >> 6);
  int lane = threadIdx.x & 63;
  const float* p = in + (size_t)row * DM;
  float v[8]; float s = 0.f, ss = 0.f;
  #pragma unroll
  for (int i = 0; i < 8; i++) {
    float x = p[lane + i * 64]; v[i] = x; s += x; ss += x * x;
  }
  #pragma unroll
  for (int off = 32; off > 0; off >>= 1) {
    s += __shfl_xor(s, off); ss += __shfl_xor(ss, off);
  }
  float mean = s * (1.f / DM);
  float var  = ss * (1.f / DM) - mean * mean;
  float rstd = rsqrtf(var + 1e-5f);
  #pragma unroll
  for (int i = 0; i < 8; i++) {
    int c = lane + i * 64;
    float y = (v[i] - mean) * rstd * g[c] + bb[c];
    if (outf) outf[(size_t)row * DM + c] = y;
    if (outb) outb[(size_t)row * DM + c] = f2bf(y);
  }
}

// ---------------------------------------------------------------------------
extern "C" void kernel_launch(void* const* d_in, const int* in_sizes, int n_in,
                              void* d_out, int out_size, void* d_ws, size_t ws_size,
                              hipStream_t stream)
{
  float* out = (float*)d_out;          // f32 output

  if (ws_size < (size_t)62918656) {    // 60 MB + safety
    fill_code_f32<<<2097152 / 256, 256, 0, stream>>>(
        out, 1200.f + (float)(ws_size >> 20));
    return;
  }

  const float* x    = (const float*)d_in[0];
  const float* tau  = (const float*)d_in[1];
  const float* del  = (const float*)d_in[2];
  const float* Wq = (const float*)d_in[4];
  const float* bq = (const float*)d_in[5];
  const float* Wk = (const float*)d_in[6];
  const float* bk = (const float*)d_in[7];
  const float* Wv = (const float*)d_in[8];
  const float* bv = (const float*)d_in[9];
  const float* Wo = (const float*)d_in[10];
  const float* bo = (const float*)d_in[11];
  const float* W1 = (const float*)d_in[12];
  const float* b1 = (const float*)d_in[13];
  const float* W2 = (const float*)d_in[14];
  const float* b2 = (const float*)d_in[15];
  const float* ln1g = (const float*)d_in[16];
  const float* ln1b = (const float*)d_in[17];
  const float* ln2g = (const float*)d_in[18];
  const float* ln2b = (const float*)d_in[19];
  const float* lnfg = (const float*)d_in[20];
  const float* lnfb = (const float*)d_in[21];

  char* ws = (char*)d_ws;
  float* sumf  = (float*)(ws + 0);          //  8 MB  fp32 residual chain (x)
  short* x16   = (short*)(ws + 8388608);    //  4 MB  bf16 x (GEMM A operand)
  short* xb16  = (short*)(ws + 12582912);   //  4 MB  LN1 out (xb)
  short* q16   = (short*)(ws + 16777216);   //  4 MB  (B,H,L,E)
  short* k16   = (short*)(ws + 20971520);   //  4 MB  (B,H,L,E)
  short* vt16  = (short*)(ws + 25165824);   //  4 MB  (B,H,E,L)
  short* at16  = (short*)(ws + 29360128);   //  4 MB  attention out (B*L, D)
  short* h16   = (short*)(ws + 33554432);   // 16 MB  FFN hidden
  short* Wqkvt = (short*)(ws + 50331648);   //  3 MB
  short* Wot   = (short*)(ws + 53477376);   //  1 MB
  short* W1t   = (short*)(ws + 54525952);   //  4 MB
  short* W2t   = (short*)(ws + 58720256);   //  4 MB  (total 60 MB)
  // Overlays (regions dead at time of use):
  short* aopart = (short*)(ws + 33554432);  // attn O partials (h16, 16 MB)
  float* alpart = (float*)(ws + 12582912);  // attn l partials (xb16, 512 KB)
  short* oppart = (short*)(ws + 33554432);  // O-proj split-K partials (h16)
  short* f2part = (short*)(ws + 16777216);  // FFN2 split-K partials
                                            //   (q16..at16, 16 MB)

  prep_weights<<<3072, 256, 0, stream>>>(Wq, Wk, Wv, Wo, W1, W2,
                                         Wqkvt, Wot, W1t, W2t);
  cast_kernel<<<NTOK * DM / 256, 256, 0, stream>>>(x, sumf, x16);

  for (int l = 0; l < 2; l++) {
    // QKV (N=1536, K=512) -- TM=64: 768 blocks, 8 BK=64 iters
    gemm_bt<64><<<64 * 12, 256, 0, stream>>>(x16, Wqkvt + l * 786432,
        NTOK, 3 * DM, DM, 1, 0,
        bq + l * DM, bk + l * DM, bv + l * DM,
        q16, k16, vt16);
    attn_v7<<<4 * NBAT * NH * (SEQ / 64), 256, 0, stream>>>(
        q16, k16, vt16, tau, del, aopart, alpart);
    attn_reduce<<<NBAT * NH * (SEQ / 64), 256, 0, stream>>>(
        aopart, alpart, at16);
    // O-proj: split-K x4 -> fused reduce + residual + LN1 (xb16)
    gemm_bt<64><<<64 * 4 * 4, 256, 0, stream>>>(at16, Wot + l * 262144,
        NTOK, DM, DM, 4, 4,
        nullptr, nullptr, nullptr,
        oppart, nullptr, nullptr);
    skred_ln<<<1024, 256, 0, stream>>>(oppart, bo + l * DM, sumf, nullptr,
        ln1g + l * DM, ln1b + l * DM, sumf, xb16, 0);
    // FFN1 + GELU (N=2048, K=512) -- TM=64: 1024 blocks, 8 BK=64 iters
    gemm_bt<64><<<64 * 16, 256, 0, stream>>>(xb16, W1t + l * 1048576,
        NTOK, DFF, DM, 1, 2,
        b1 + l * DFF, nullptr, nullptr,
        h16, nullptr, nullptr);
    // FFN2: split-K x4 -> fused reduce + xb residual + LN2 (sumf + x16)
    gemm_bt<64><<<64 * 4 * 4, 256, 0, stream>>>(h16, W2t + l * 1048576,
        NTOK, DM, DFF, 4, 4,
        nullptr, nullptr, nullptr,
        f2part, nullptr, nullptr);
    skred_ln<<<1024, 256, 0, stream>>>(f2part, b2 + l * DM, nullptr, xb16,
        ln2g + l * DM, ln2b + l * DM, sumf, x16, 1);
  }
  ln_kernel<<<NTOK / 4, 256, 0, stream>>>(sumf, lnfg, lnfb, out, nullptr);
}